// Round 6
// baseline (503.113 us; speedup 1.0000x reference)
//
#include <hip/hip_runtime.h>
#include <hip/hip_bf16.h>
#include <stdint.h>

#define NB 4
#define NS 2048
#define ND 1024
#define NH 16
#define NHS 64
#define NEG_BIG (-1e30f)
// 1/sqrt(HS) * log2(e): folds softmax exp->exp2 into Q scaling (exactly softmax-invariant)
#define Q_SCALE 0.18033688011112042f

typedef __bf16 bf16x8 __attribute__((ext_vector_type(8)));
typedef float floatx4 __attribute__((ext_vector_type(4)));

static constexpr size_t WSLAB = (size_t)NH * ND * NHS;        // 2^20 elems per weight mat
static constexpr size_t QSLAB = (size_t)NB * NH * NS * NHS;   // 8M elems per QKV/Y slab
static constexpr size_t XSLAB = (size_t)NB * NS * ND;         // 8M elems (x as bf16)

__device__ __forceinline__ uint16_t f2b(float f) {
    union { __hip_bfloat16 h; uint16_t u; } cv;
    cv.h = __float2bfloat16(f);
    return cv.u;
}

// ---------------- kernel A: x fp32 -> bf16 ----------------
__global__ __launch_bounds__(256) void k_convert_x(
    const float* __restrict__ x, uint16_t* __restrict__ xb) {
  size_t i0 = ((size_t)blockIdx.x * 256 + threadIdx.x) * 8;
  float4 f0 = *(const float4*)&x[i0];
  float4 f1 = *(const float4*)&x[i0 + 4];
  __align__(16) uint16_t tmp[8];
  tmp[0] = f2b(f0.x); tmp[1] = f2b(f0.y); tmp[2] = f2b(f0.z); tmp[3] = f2b(f0.w);
  tmp[4] = f2b(f1.x); tmp[5] = f2b(f1.y); tmp[6] = f2b(f1.z); tmp[7] = f2b(f1.w);
  *(uint4*)&xb[i0] = *(uint4*)tmp;
}

// ---------------- kernel 0: weight convert+transpose (LDS tiled) ----------------
__global__ __launch_bounds__(256) void k_transpose(
    const float* __restrict__ Wq, const float* __restrict__ Wk,
    const float* __restrict__ Wv, const float* __restrict__ Wo,
    uint16_t* __restrict__ ws) {
  __shared__ __align__(16) uint16_t T[64][72];
  int bid = blockIdx.x;
  int tid = threadIdx.x;
  const float* src; uint16_t* dst;
  int srcStride, dstStride, r0, c0;
  if (bid < 768) {
    int mat = bid >> 8;
    int rem = bid & 255;
    int h = rem >> 4, dt = rem & 15;
    const float* W = (mat == 0) ? Wq : (mat == 1) ? Wk : Wv;
    src = W + (size_t)h * (ND * NHS);
    dst = ws + (size_t)mat * WSLAB + (size_t)h * (NHS * ND);
    srcStride = NHS; dstStride = ND;
    r0 = dt * 64; c0 = 0;
  } else {
    int rem = bid - 768;
    int dt = rem >> 4, et = rem & 15;
    src = Wo; dst = ws + 3 * WSLAB;
    srcStride = ND; dstStride = ND;
    r0 = dt * 64; c0 = et * 64;
  }
  for (int u = tid; u < 1024; u += 256) {
    int row = u >> 4, cq = u & 15;
    float4 f = *(const float4*)&src[(size_t)(r0 + row) * srcStride + c0 + cq * 4];
    uint16_t* p = &T[row][cq * 4];
    p[0] = f2b(f.x); p[1] = f2b(f.y); p[2] = f2b(f.z); p[3] = f2b(f.w);
  }
  __syncthreads();
  for (int u = tid; u < 512; u += 256) {
    int c = u >> 3, cg = u & 7;
    __align__(16) uint16_t tmp[8];
    for (int j = 0; j < 8; j++) tmp[j] = T[cg * 8 + j][c];
    *(uint4*)&dst[(size_t)(c0 + c) * dstStride + r0 + cg * 8] = *(uint4*)tmp;
  }
}

// ---------------- kernel 1: QKV projection GEMM (Q pre-scaled by 1/8*log2e) ----------------
__global__ __launch_bounds__(256) void k_qkv(
    const uint16_t* __restrict__ x, const uint16_t* __restrict__ wt,
    uint16_t* __restrict__ qkv) {
  __shared__ __align__(16) uint16_t As[128][72];
  __shared__ __align__(16) uint16_t Bs[64][72];
  int mat = blockIdx.z;
  int bh = blockIdx.y;
  int b = bh >> 4, h = bh & 15;
  int m0 = blockIdx.x * 128;
  const uint16_t* xb = x + (size_t)b * (NS * ND);
  const uint16_t* wh = wt + (size_t)mat * WSLAB + (size_t)h * (NHS * ND);
  int tid = threadIdx.x;
  int wv = tid >> 6, lane = tid & 63, quad = lane >> 4, l16 = lane & 15;

  floatx4 acc[2][4];
  for (int i = 0; i < 2; i++)
    for (int j = 0; j < 4; j++) acc[i][j] = (floatx4){0.f, 0.f, 0.f, 0.f};

  for (int k0 = 0; k0 < ND; k0 += 64) {
    for (int u = tid; u < 1024; u += 256) {
      int row = u >> 3, cg = u & 7;
      *(uint4*)&As[row][cg * 8] =
          *(const uint4*)&xb[(size_t)(m0 + row) * ND + k0 + cg * 8];
    }
    for (int u = tid; u < 512; u += 256) {
      int row = u >> 3, cg = u & 7;
      *(uint4*)&Bs[row][cg * 8] =
          *(const uint4*)&wh[(size_t)row * ND + k0 + cg * 8];
    }
    __syncthreads();
    for (int kk = 0; kk < 2; kk++) {
      bf16x8 a0 = *(const bf16x8*)&As[wv * 32 + l16][kk * 32 + quad * 8];
      bf16x8 a1 = *(const bf16x8*)&As[wv * 32 + 16 + l16][kk * 32 + quad * 8];
      for (int ct = 0; ct < 4; ct++) {
        bf16x8 bb = *(const bf16x8*)&Bs[ct * 16 + l16][kk * 32 + quad * 8];
        acc[0][ct] = __builtin_amdgcn_mfma_f32_16x16x32_bf16(a0, bb, acc[0][ct], 0, 0, 0);
        acc[1][ct] = __builtin_amdgcn_mfma_f32_16x16x32_bf16(a1, bb, acc[1][ct], 0, 0, 0);
      }
    }
    __syncthreads();
  }
  float scale = (mat == 0) ? Q_SCALE : 1.0f;
  uint16_t* out = qkv + (size_t)mat * QSLAB + (size_t)bh * (NS * NHS);
  for (int rt = 0; rt < 2; rt++)
    for (int ct = 0; ct < 4; ct++)
      for (int r = 0; r < 4; r++) {
        int s = m0 + wv * 32 + rt * 16 + quad * 4 + r;
        int e = ct * 16 + l16;
        out[(size_t)s * NHS + e] = f2b(acc[rt][ct][r] * scale);
      }
}

// ---------------- kernel 1b: V -> V^T ([B,H,S,HS] -> [B,H,HS,S]) ----------------
__global__ __launch_bounds__(256) void k_vt(
    const uint16_t* __restrict__ v, uint16_t* __restrict__ vt) {
  __shared__ __align__(16) uint16_t T[64][72];
  int bh = blockIdx.y;
  int s0 = blockIdx.x * 64;
  int tid = threadIdx.x;
  const uint16_t* src = v + (size_t)bh * (NS * NHS);
  uint16_t* dst = vt + (size_t)bh * (NS * NHS);
  for (int u = tid; u < 512; u += 256) {
    int row = u >> 3, cg = u & 7;
    *(uint4*)&T[row][cg * 8] =
        *(const uint4*)&src[(size_t)(s0 + row) * NHS + cg * 8];
  }
  __syncthreads();
  for (int u = tid; u < 512; u += 256) {
    int e = u >> 3, cg = u & 7;
    __align__(16) uint16_t tmp[8];
    for (int j = 0; j < 8; j++) tmp[j] = T[cg * 8 + j][e];
    *(uint4*)&dst[(size_t)e * NS + s0 + cg * 8] = *(uint4*)tmp;
  }
}

// ---------------- kernel 2: causal attention, static softmax, no barriers ----------------
// grid (16, NB*NH), block 256 (4 waves). Wave wv handles rows [wv*16,+16) of paired
// q-tiles ta=blockIdx.x, tb=31-ta (33 key-tiles total, perfectly balanced).
// K/V fragments straight from global (L2-resident); LDS only for per-wave P transpose.
__global__ __launch_bounds__(256) void k_attn(
    const uint16_t* __restrict__ Q, const uint16_t* __restrict__ K,
    const uint16_t* __restrict__ VT, uint16_t* __restrict__ Y) {
  __shared__ __align__(16) uint16_t Ps[4][2][16][72];  // [wave][A/B][row][col]
  int bh = blockIdx.y;
  int b = bh >> 4, h = bh & 15;
  int ta = blockIdx.x;       // 0..15
  int tb = 31 - ta;          // 16..31
  const uint16_t* Qp = Q + (size_t)bh * (NS * NHS);
  const uint16_t* Kp = K + (size_t)bh * (NS * NHS);
  const uint16_t* Vp = VT + (size_t)bh * (NS * NHS);  // [e][key]
  int tid = threadIdx.x;
  int wv = tid >> 6, lane = tid & 63, quad = lane >> 4, l16 = lane & 15;

  // Q fragments from global (A-layout: m=l16, k=quad*8+j)
  int rA = ta * 64 + wv * 16 + l16;
  int rB = tb * 64 + wv * 16 + l16;
  bf16x8 aqA0 = *(const bf16x8*)&Qp[(size_t)rA * NHS + quad * 8];
  bf16x8 aqA1 = *(const bf16x8*)&Qp[(size_t)rA * NHS + 32 + quad * 8];
  bf16x8 aqB0 = *(const bf16x8*)&Qp[(size_t)rB * NHS + quad * 8];
  bf16x8 aqB1 = *(const bf16x8*)&Qp[(size_t)rB * NHS + 32 + quad * 8];

  float lA[4] = {0.f, 0.f, 0.f, 0.f}, lB[4] = {0.f, 0.f, 0.f, 0.f};
  floatx4 oA[4], oB[4];
  for (int ct = 0; ct < 4; ct++) {
    oA[ct] = (floatx4){0.f, 0.f, 0.f, 0.f};
    oB[ct] = (floatx4){0.f, 0.f, 0.f, 0.f};
  }

  for (int kt = 0; kt <= tb; kt++) {
    bool doA = (kt <= ta);  // uniform across block
    // ---- QK^T (K fragments shared between A and B tiles) ----
    floatx4 sA[4], sB[4];
    for (int ct = 0; ct < 4; ct++) {
      const uint16_t* kr = &Kp[(size_t)(kt * 64 + ct * 16 + l16) * NHS + quad * 8];
      bf16x8 kb0 = *(const bf16x8*)kr;
      bf16x8 kb1 = *(const bf16x8*)(kr + 32);
      floatx4 c = (floatx4){0.f, 0.f, 0.f, 0.f};
      c = __builtin_amdgcn_mfma_f32_16x16x32_bf16(aqB0, kb0, c, 0, 0, 0);
      c = __builtin_amdgcn_mfma_f32_16x16x32_bf16(aqB1, kb1, c, 0, 0, 0);
      sB[ct] = c;
      if (doA) {
        floatx4 d = (floatx4){0.f, 0.f, 0.f, 0.f};
        d = __builtin_amdgcn_mfma_f32_16x16x32_bf16(aqA0, kb0, d, 0, 0, 0);
        d = __builtin_amdgcn_mfma_f32_16x16x32_bf16(aqA1, kb1, d, 0, 0, 0);
        sA[ct] = d;
      }
    }
    // ---- diagonal causal mask (wave-uniform branches) ----
    if (kt == tb) {
      int qrb = tb * 64 + wv * 16 + quad * 4;
      for (int ct = 0; ct < 4; ct++) {
        int kg = kt * 64 + ct * 16 + l16;
        for (int r = 0; r < 4; r++)
          sB[ct][r] = (kg <= qrb + r) ? sB[ct][r] : NEG_BIG;
      }
    }
    if (doA && kt == ta) {
      int qrb = ta * 64 + wv * 16 + quad * 4;
      for (int ct = 0; ct < 4; ct++) {
        int kg = kt * 64 + ct * 16 + l16;
        for (int r = 0; r < 4; r++)
          sA[ct][r] = (kg <= qrb + r) ? sA[ct][r] : NEG_BIG;
      }
    }
    // ---- static softmax: p = exp2(s) (Q pre-scaled by log2e/8), deferred row-sum ----
    for (int ct = 0; ct < 4; ct++)
      for (int r = 0; r < 4; r++) {
        float p = __builtin_amdgcn_exp2f(sB[ct][r]);
        lB[r] += p;
        Ps[wv][1][quad * 4 + r][ct * 16 + l16] = f2b(p);
      }
    if (doA)
      for (int ct = 0; ct < 4; ct++)
        for (int r = 0; r < 4; r++) {
          float p = __builtin_amdgcn_exp2f(sA[ct][r]);
          lA[r] += p;
          Ps[wv][0][quad * 4 + r][ct * 16 + l16] = f2b(p);
        }
    // ---- P C-layout -> A-layout (per-wave LDS round trip, same-wave ordering) ----
    bf16x8 apB0 = *(const bf16x8*)&Ps[wv][1][l16][quad * 8];
    bf16x8 apB1 = *(const bf16x8*)&Ps[wv][1][l16][32 + quad * 8];
    bf16x8 apA0, apA1;
    if (doA) {
      apA0 = *(const bf16x8*)&Ps[wv][0][l16][quad * 8];
      apA1 = *(const bf16x8*)&Ps[wv][0][l16][32 + quad * 8];
    }
    // ---- PV (V fragments shared) ----
    for (int ct = 0; ct < 4; ct++) {
      const uint16_t* vr = &Vp[(size_t)(ct * 16 + l16) * NS + kt * 64 + quad * 8];
      bf16x8 vb0 = *(const bf16x8*)vr;
      bf16x8 vb1 = *(const bf16x8*)(vr + 32);
      oB[ct] = __builtin_amdgcn_mfma_f32_16x16x32_bf16(apB0, vb0, oB[ct], 0, 0, 0);
      oB[ct] = __builtin_amdgcn_mfma_f32_16x16x32_bf16(apB1, vb1, oB[ct], 0, 0, 0);
      if (doA) {
        oA[ct] = __builtin_amdgcn_mfma_f32_16x16x32_bf16(apA0, vb0, oA[ct], 0, 0, 0);
        oA[ct] = __builtin_amdgcn_mfma_f32_16x16x32_bf16(apA1, vb1, oA[ct], 0, 0, 0);
      }
    }
  }
  // ---- one-time row-sum reduction across the 16 column-lanes ----
  for (int off = 1; off < 16; off <<= 1)
    for (int r = 0; r < 4; r++) {
      lA[r] += __shfl_xor(lA[r], off, 64);
      lB[r] += __shfl_xor(lB[r], off, 64);
    }
  uint16_t* yb = Y + (size_t)b * NS * ND + (size_t)h * NHS;
  for (int ct = 0; ct < 4; ct++)
    for (int r = 0; r < 4; r++) {
      int sA_ = ta * 64 + wv * 16 + quad * 4 + r;
      int sB_ = tb * 64 + wv * 16 + quad * 4 + r;
      yb[(size_t)sA_ * ND + ct * 16 + l16] = f2b(oA[ct][r] / lA[r]);
      yb[(size_t)sB_ * ND + ct * 16 + l16] = f2b(oB[ct][r] / lB[r]);
    }
}

// ---------------- kernel 3: output projection + bias (fp32 out) ----------------
__global__ __launch_bounds__(256) void k_proj(
    const uint16_t* __restrict__ y, const uint16_t* __restrict__ wot,
    const float* __restrict__ bo, float* __restrict__ out) {
  __shared__ __align__(16) uint16_t As[128][72];
  __shared__ __align__(16) uint16_t Bs[64][72];
  int m0 = blockIdx.x * 128;
  int n0 = blockIdx.y * 64;
  int tid = threadIdx.x;
  int wv = tid >> 6, lane = tid & 63, quad = lane >> 4, l16 = lane & 15;

  floatx4 acc[2][4];
  for (int i = 0; i < 2; i++)
    for (int j = 0; j < 4; j++) acc[i][j] = (floatx4){0.f, 0.f, 0.f, 0.f};

  for (int k0 = 0; k0 < ND; k0 += 64) {
    for (int u = tid; u < 1024; u += 256) {
      int row = u >> 3, cg = u & 7;
      *(uint4*)&As[row][cg * 8] =
          *(const uint4*)&y[(size_t)(m0 + row) * ND + k0 + cg * 8];
    }
    for (int u = tid; u < 512; u += 256) {
      int row = u >> 3, cg = u & 7;
      *(uint4*)&Bs[row][cg * 8] =
          *(const uint4*)&wot[(size_t)(n0 + row) * ND + k0 + cg * 8];
    }
    __syncthreads();
    for (int kk = 0; kk < 2; kk++) {
      bf16x8 a0 = *(const bf16x8*)&As[wv * 32 + l16][kk * 32 + quad * 8];
      bf16x8 a1 = *(const bf16x8*)&As[wv * 32 + 16 + l16][kk * 32 + quad * 8];
      for (int ct = 0; ct < 4; ct++) {
        bf16x8 bb = *(const bf16x8*)&Bs[ct * 16 + l16][kk * 32 + quad * 8];
        acc[0][ct] = __builtin_amdgcn_mfma_f32_16x16x32_bf16(a0, bb, acc[0][ct], 0, 0, 0);
        acc[1][ct] = __builtin_amdgcn_mfma_f32_16x16x32_bf16(a1, bb, acc[1][ct], 0, 0, 0);
      }
    }
    __syncthreads();
  }
  for (int rt = 0; rt < 2; rt++)
    for (int ct = 0; ct < 4; ct++)
      for (int r = 0; r < 4; r++) {
        int s = m0 + wv * 32 + rt * 16 + quad * 4 + r;
        int n = n0 + ct * 16 + l16;
        out[(size_t)s * ND + n] = acc[rt][ct][r] + bo[n];
      }
}

extern "C" void kernel_launch(void* const* d_in, const int* in_sizes, int n_in,
                              void* d_out, int out_size, void* d_ws, size_t ws_size,
                              hipStream_t stream) {
  const float* x  = (const float*)d_in[0];
  const float* Wq = (const float*)d_in[1];
  const float* Wk = (const float*)d_in[2];
  const float* Wv = (const float*)d_in[3];
  const float* Wo = (const float*)d_in[4];
  const float* bo = (const float*)d_in[5];
  uint16_t* ws = (uint16_t*)d_ws;

  uint16_t* wt = ws;                       // 4 * WSLAB bf16 (Wq_t, Wk_t, Wv_t, Wo_t)
  uint16_t* xb = ws + 4 * WSLAB;           // XSLAB bf16
  uint16_t* q  = xb + XSLAB;               // QSLAB each
  uint16_t* k  = q + QSLAB;
  uint16_t* v  = k + QSLAB;
  uint16_t* y  = v + QSLAB;
  uint16_t* vt = y + QSLAB;                // QSLAB (V transposed)

  k_convert_x<<<dim3(XSLAB / (256 * 8)), dim3(256), 0, stream>>>(x, xb);
  k_transpose<<<dim3(1024), dim3(256), 0, stream>>>(Wq, Wk, Wv, Wo, wt);
  k_qkv<<<dim3(NS / 128, NB * NH, 3), dim3(256), 0, stream>>>(xb, wt, q);
  k_vt<<<dim3(NS / 64, NB * NH), dim3(256), 0, stream>>>(v, vt);
  k_attn<<<dim3(16, NB * NH), dim3(256), 0, stream>>>(q, k, vt, y);
  k_proj<<<dim3(NB * NS / 128, ND / 64), dim3(256), 0, stream>>>(y, wt + 3 * WSLAB, bo, (float*)d_out);
}

// Round 7
// 417.575 us; speedup vs baseline: 1.2048x; 1.2048x over previous
//
#include <hip/hip_runtime.h>
#include <hip/hip_bf16.h>
#include <stdint.h>

#define NB 4
#define NS 2048
#define ND 1024
#define NH 16
#define NHS 64
#define NEG_BIG (-1e30f)
// 1/sqrt(HS) * log2(e): folds softmax exp->exp2 into Q scaling (exactly softmax-invariant)
#define Q_SCALE 0.18033688011112042f

typedef __bf16 bf16x8 __attribute__((ext_vector_type(8)));
typedef float floatx4 __attribute__((ext_vector_type(4)));

static constexpr size_t WSLAB = (size_t)NH * ND * NHS;        // 2^20 elems per weight mat
static constexpr size_t QSLAB = (size_t)NB * NH * NS * NHS;   // 8M elems per QKV/Y slab
static constexpr size_t XSLAB = (size_t)NB * NS * ND;         // 8M elems (x as bf16)

__device__ __forceinline__ uint16_t f2b(float f) {
    union { __hip_bfloat16 h; uint16_t u; } cv;
    cv.h = __float2bfloat16(f);
    return cv.u;
}

// ---------------- kernel A: x fp32 -> bf16 ----------------
__global__ __launch_bounds__(256) void k_convert_x(
    const float* __restrict__ x, uint16_t* __restrict__ xb) {
  size_t i0 = ((size_t)blockIdx.x * 256 + threadIdx.x) * 8;
  float4 f0 = *(const float4*)&x[i0];
  float4 f1 = *(const float4*)&x[i0 + 4];
  __align__(16) uint16_t tmp[8];
  tmp[0] = f2b(f0.x); tmp[1] = f2b(f0.y); tmp[2] = f2b(f0.z); tmp[3] = f2b(f0.w);
  tmp[4] = f2b(f1.x); tmp[5] = f2b(f1.y); tmp[6] = f2b(f1.z); tmp[7] = f2b(f1.w);
  *(uint4*)&xb[i0] = *(uint4*)tmp;
}

// ---------------- kernel 0: weight convert+transpose (LDS tiled) ----------------
__global__ __launch_bounds__(256) void k_transpose(
    const float* __restrict__ Wq, const float* __restrict__ Wk,
    const float* __restrict__ Wv, const float* __restrict__ Wo,
    uint16_t* __restrict__ ws) {
  __shared__ __align__(16) uint16_t T[64][72];
  int bid = blockIdx.x;
  int tid = threadIdx.x;
  const float* src; uint16_t* dst;
  int srcStride, dstStride, r0, c0;
  if (bid < 768) {
    int mat = bid >> 8;
    int rem = bid & 255;
    int h = rem >> 4, dt = rem & 15;
    const float* W = (mat == 0) ? Wq : (mat == 1) ? Wk : Wv;
    src = W + (size_t)h * (ND * NHS);
    dst = ws + (size_t)mat * WSLAB + (size_t)h * (NHS * ND);
    srcStride = NHS; dstStride = ND;
    r0 = dt * 64; c0 = 0;
  } else {
    int rem = bid - 768;
    int dt = rem >> 4, et = rem & 15;
    src = Wo; dst = ws + 3 * WSLAB;
    srcStride = ND; dstStride = ND;
    r0 = dt * 64; c0 = et * 64;
  }
  for (int u = tid; u < 1024; u += 256) {
    int row = u >> 4, cq = u & 15;
    float4 f = *(const float4*)&src[(size_t)(r0 + row) * srcStride + c0 + cq * 4];
    uint16_t* p = &T[row][cq * 4];
    p[0] = f2b(f.x); p[1] = f2b(f.y); p[2] = f2b(f.z); p[3] = f2b(f.w);
  }
  __syncthreads();
  for (int u = tid; u < 512; u += 256) {
    int c = u >> 3, cg = u & 7;
    __align__(16) uint16_t tmp[8];
    for (int j = 0; j < 8; j++) tmp[j] = T[cg * 8 + j][c];
    *(uint4*)&dst[(size_t)(c0 + c) * dstStride + r0 + cg * 8] = *(uint4*)tmp;
  }
}

// ---------------- kernel 1: QKV projection GEMM (Q pre-scaled by 1/8*log2e) ----------------
__global__ __launch_bounds__(256) void k_qkv(
    const uint16_t* __restrict__ x, const uint16_t* __restrict__ wt,
    uint16_t* __restrict__ qkv) {
  __shared__ __align__(16) uint16_t As[128][72];
  __shared__ __align__(16) uint16_t Bs[64][72];
  int mat = blockIdx.z;
  int bh = blockIdx.y;
  int b = bh >> 4, h = bh & 15;
  int m0 = blockIdx.x * 128;
  const uint16_t* xb = x + (size_t)b * (NS * ND);
  const uint16_t* wh = wt + (size_t)mat * WSLAB + (size_t)h * (NHS * ND);
  int tid = threadIdx.x;
  int wv = tid >> 6, lane = tid & 63, quad = lane >> 4, l16 = lane & 15;

  floatx4 acc[2][4];
  for (int i = 0; i < 2; i++)
    for (int j = 0; j < 4; j++) acc[i][j] = (floatx4){0.f, 0.f, 0.f, 0.f};

  for (int k0 = 0; k0 < ND; k0 += 64) {
    for (int u = tid; u < 1024; u += 256) {
      int row = u >> 3, cg = u & 7;
      *(uint4*)&As[row][cg * 8] =
          *(const uint4*)&xb[(size_t)(m0 + row) * ND + k0 + cg * 8];
    }
    for (int u = tid; u < 512; u += 256) {
      int row = u >> 3, cg = u & 7;
      *(uint4*)&Bs[row][cg * 8] =
          *(const uint4*)&wh[(size_t)row * ND + k0 + cg * 8];
    }
    __syncthreads();
    for (int kk = 0; kk < 2; kk++) {
      bf16x8 a0 = *(const bf16x8*)&As[wv * 32 + l16][kk * 32 + quad * 8];
      bf16x8 a1 = *(const bf16x8*)&As[wv * 32 + 16 + l16][kk * 32 + quad * 8];
      for (int ct = 0; ct < 4; ct++) {
        bf16x8 bb = *(const bf16x8*)&Bs[ct * 16 + l16][kk * 32 + quad * 8];
        acc[0][ct] = __builtin_amdgcn_mfma_f32_16x16x32_bf16(a0, bb, acc[0][ct], 0, 0, 0);
        acc[1][ct] = __builtin_amdgcn_mfma_f32_16x16x32_bf16(a1, bb, acc[1][ct], 0, 0, 0);
      }
    }
    __syncthreads();
  }
  float scale = (mat == 0) ? Q_SCALE : 1.0f;
  uint16_t* out = qkv + (size_t)mat * QSLAB + (size_t)bh * (NS * NHS);
  for (int rt = 0; rt < 2; rt++)
    for (int ct = 0; ct < 4; ct++)
      for (int r = 0; r < 4; r++) {
        int s = m0 + wv * 32 + rt * 16 + quad * 4 + r;
        int e = ct * 16 + l16;
        out[(size_t)s * NHS + e] = f2b(acc[rt][ct][r] * scale);
      }
}

// ---------------- kernel 1b: V -> V^T ([B,H,S,HS] -> [B,H,HS,S]) ----------------
__global__ __launch_bounds__(256) void k_vt(
    const uint16_t* __restrict__ v, uint16_t* __restrict__ vt) {
  __shared__ __align__(16) uint16_t T[64][72];
  int bh = blockIdx.y;
  int s0 = blockIdx.x * 64;
  int tid = threadIdx.x;
  const uint16_t* src = v + (size_t)bh * (NS * NHS);
  uint16_t* dst = vt + (size_t)bh * (NS * NHS);
  for (int u = tid; u < 512; u += 256) {
    int row = u >> 3, cg = u & 7;
    *(uint4*)&T[row][cg * 8] =
        *(const uint4*)&src[(size_t)(s0 + row) * NHS + cg * 8];
  }
  __syncthreads();
  for (int u = tid; u < 512; u += 256) {
    int e = u >> 3, cg = u & 7;
    __align__(16) uint16_t tmp[8];
    for (int j = 0; j < 8; j++) tmp[j] = T[cg * 8 + j][e];
    *(uint4*)&dst[(size_t)e * NS + s0 + cg * 8] = *(uint4*)tmp;
  }
}

// ---------------- kernel 2: causal attention, LDS-staged K/V + static softmax ----------------
// grid (16, NB*NH), block 256 (4 waves). Paired q-tiles ta=blockIdx.x, tb=31-ta
// (33 key-tiles/block, balanced). K/V staged in LDS once per tile (shared by all
// 4 waves and both q-tiles); static softmax (exp2, deferred row-sum, no reductions
// in the loop, no online rescale).
__global__ __launch_bounds__(256) void k_attn(
    const uint16_t* __restrict__ Q, const uint16_t* __restrict__ K,
    const uint16_t* __restrict__ VT, uint16_t* __restrict__ Y) {
  __shared__ __align__(16) uint16_t Ks[64][72];
  __shared__ __align__(16) uint16_t Vs[64][72];        // V^T tile: [e][key]
  __shared__ __align__(16) uint16_t Ps[4][2][16][72];  // [wave][A/B][row][col]
  int bh = blockIdx.y;
  int b = bh >> 4, h = bh & 15;
  int ta = blockIdx.x;       // 0..15
  int tb = 31 - ta;          // 16..31
  const uint16_t* Qp = Q + (size_t)bh * (NS * NHS);
  const uint16_t* Kp = K + (size_t)bh * (NS * NHS);
  const uint16_t* Vp = VT + (size_t)bh * (NS * NHS);  // [e][key]
  int tid = threadIdx.x;
  int wv = tid >> 6, lane = tid & 63, quad = lane >> 4, l16 = lane & 15;

  // Q fragments from global (A-layout: m=l16, k=quad*8+j)
  int rA = ta * 64 + wv * 16 + l16;
  int rB = tb * 64 + wv * 16 + l16;
  bf16x8 aqA0 = *(const bf16x8*)&Qp[(size_t)rA * NHS + quad * 8];
  bf16x8 aqA1 = *(const bf16x8*)&Qp[(size_t)rA * NHS + 32 + quad * 8];
  bf16x8 aqB0 = *(const bf16x8*)&Qp[(size_t)rB * NHS + quad * 8];
  bf16x8 aqB1 = *(const bf16x8*)&Qp[(size_t)rB * NHS + 32 + quad * 8];

  float lA[4] = {0.f, 0.f, 0.f, 0.f}, lB[4] = {0.f, 0.f, 0.f, 0.f};
  floatx4 oA[4], oB[4];
  for (int ct = 0; ct < 4; ct++) {
    oA[ct] = (floatx4){0.f, 0.f, 0.f, 0.f};
    oB[ct] = (floatx4){0.f, 0.f, 0.f, 0.f};
  }

  for (int kt = 0; kt <= tb; kt++) {
    bool doA = (kt <= ta);  // uniform across block
    __syncthreads();  // prior readers of Ks/Vs done
    for (int u = tid; u < 512; u += 256) {
      int row = u >> 3, cg = u & 7;
      *(uint4*)&Ks[row][cg * 8] =
          *(const uint4*)&Kp[(size_t)(kt * 64 + row) * NHS + cg * 8];
    }
    for (int u = tid; u < 512; u += 256) {
      int row = u >> 3, cg = u & 7;   // row = e, cols = keys
      *(uint4*)&Vs[row][cg * 8] =
          *(const uint4*)&Vp[(size_t)row * NS + kt * 64 + cg * 8];
    }
    __syncthreads();

    // ---- QK^T (K fragments from LDS, shared between A and B q-tiles) ----
    floatx4 sA[4], sB[4];
    for (int ct = 0; ct < 4; ct++) {
      bf16x8 kb0 = *(const bf16x8*)&Ks[ct * 16 + l16][quad * 8];
      bf16x8 kb1 = *(const bf16x8*)&Ks[ct * 16 + l16][32 + quad * 8];
      floatx4 c = (floatx4){0.f, 0.f, 0.f, 0.f};
      c = __builtin_amdgcn_mfma_f32_16x16x32_bf16(aqB0, kb0, c, 0, 0, 0);
      c = __builtin_amdgcn_mfma_f32_16x16x32_bf16(aqB1, kb1, c, 0, 0, 0);
      sB[ct] = c;
      if (doA) {
        floatx4 d = (floatx4){0.f, 0.f, 0.f, 0.f};
        d = __builtin_amdgcn_mfma_f32_16x16x32_bf16(aqA0, kb0, d, 0, 0, 0);
        d = __builtin_amdgcn_mfma_f32_16x16x32_bf16(aqA1, kb1, d, 0, 0, 0);
        sA[ct] = d;
      }
    }
    // ---- diagonal causal mask (wave-uniform branches) ----
    if (kt == tb) {
      int qrb = tb * 64 + wv * 16 + quad * 4;
      for (int ct = 0; ct < 4; ct++) {
        int kg = kt * 64 + ct * 16 + l16;
        for (int r = 0; r < 4; r++)
          sB[ct][r] = (kg <= qrb + r) ? sB[ct][r] : NEG_BIG;
      }
    }
    if (doA && kt == ta) {
      int qrb = ta * 64 + wv * 16 + quad * 4;
      for (int ct = 0; ct < 4; ct++) {
        int kg = kt * 64 + ct * 16 + l16;
        for (int r = 0; r < 4; r++)
          sA[ct][r] = (kg <= qrb + r) ? sA[ct][r] : NEG_BIG;
      }
    }
    // ---- static softmax: p = exp2(s), deferred row-sum ----
    for (int ct = 0; ct < 4; ct++)
      for (int r = 0; r < 4; r++) {
        float p = __builtin_amdgcn_exp2f(sB[ct][r]);
        lB[r] += p;
        Ps[wv][1][quad * 4 + r][ct * 16 + l16] = f2b(p);
      }
    if (doA)
      for (int ct = 0; ct < 4; ct++)
        for (int r = 0; r < 4; r++) {
          float p = __builtin_amdgcn_exp2f(sA[ct][r]);
          lA[r] += p;
          Ps[wv][0][quad * 4 + r][ct * 16 + l16] = f2b(p);
        }
    // ---- P C-layout -> A-layout (per-wave LDS round trip, same-wave ordering) ----
    bf16x8 apB0 = *(const bf16x8*)&Ps[wv][1][l16][quad * 8];
    bf16x8 apB1 = *(const bf16x8*)&Ps[wv][1][l16][32 + quad * 8];
    bf16x8 apA0, apA1;
    if (doA) {
      apA0 = *(const bf16x8*)&Ps[wv][0][l16][quad * 8];
      apA1 = *(const bf16x8*)&Ps[wv][0][l16][32 + quad * 8];
    }
    // ---- PV (V fragments from LDS, shared) ----
    for (int ct = 0; ct < 4; ct++) {
      bf16x8 vb0 = *(const bf16x8*)&Vs[ct * 16 + l16][quad * 8];
      bf16x8 vb1 = *(const bf16x8*)&Vs[ct * 16 + l16][32 + quad * 8];
      oB[ct] = __builtin_amdgcn_mfma_f32_16x16x32_bf16(apB0, vb0, oB[ct], 0, 0, 0);
      oB[ct] = __builtin_amdgcn_mfma_f32_16x16x32_bf16(apB1, vb1, oB[ct], 0, 0, 0);
      if (doA) {
        oA[ct] = __builtin_amdgcn_mfma_f32_16x16x32_bf16(apA0, vb0, oA[ct], 0, 0, 0);
        oA[ct] = __builtin_amdgcn_mfma_f32_16x16x32_bf16(apA1, vb1, oA[ct], 0, 0, 0);
      }
    }
  }
  // ---- one-time row-sum reduction across the 16 column-lanes ----
  for (int off = 1; off < 16; off <<= 1)
    for (int r = 0; r < 4; r++) {
      lA[r] += __shfl_xor(lA[r], off, 64);
      lB[r] += __shfl_xor(lB[r], off, 64);
    }
  uint16_t* yb = Y + (size_t)b * NS * ND + (size_t)h * NHS;
  for (int ct = 0; ct < 4; ct++)
    for (int r = 0; r < 4; r++) {
      int sA_ = ta * 64 + wv * 16 + quad * 4 + r;
      int sB_ = tb * 64 + wv * 16 + quad * 4 + r;
      yb[(size_t)sA_ * ND + ct * 16 + l16] = f2b(oA[ct][r] / lA[r]);
      yb[(size_t)sB_ * ND + ct * 16 + l16] = f2b(oB[ct][r] / lB[r]);
    }
}

// ---------------- kernel 3: output projection + bias (fp32 out) ----------------
__global__ __launch_bounds__(256) void k_proj(
    const uint16_t* __restrict__ y, const uint16_t* __restrict__ wot,
    const float* __restrict__ bo, float* __restrict__ out) {
  __shared__ __align__(16) uint16_t As[128][72];
  __shared__ __align__(16) uint16_t Bs[64][72];
  int m0 = blockIdx.x * 128;
  int n0 = blockIdx.y * 64;
  int tid = threadIdx.x;
  int wv = tid >> 6, lane = tid & 63, quad = lane >> 4, l16 = lane & 15;

  floatx4 acc[2][4];
  for (int i = 0; i < 2; i++)
    for (int j = 0; j < 4; j++) acc[i][j] = (floatx4){0.f, 0.f, 0.f, 0.f};

  for (int k0 = 0; k0 < ND; k0 += 64) {
    for (int u = tid; u < 1024; u += 256) {
      int row = u >> 3, cg = u & 7;
      *(uint4*)&As[row][cg * 8] =
          *(const uint4*)&y[(size_t)(m0 + row) * ND + k0 + cg * 8];
    }
    for (int u = tid; u < 512; u += 256) {
      int row = u >> 3, cg = u & 7;
      *(uint4*)&Bs[row][cg * 8] =
          *(const uint4*)&wot[(size_t)(n0 + row) * ND + k0 + cg * 8];
    }
    __syncthreads();
    for (int kk = 0; kk < 2; kk++) {
      bf16x8 a0 = *(const bf16x8*)&As[wv * 32 + l16][kk * 32 + quad * 8];
      bf16x8 a1 = *(const bf16x8*)&As[wv * 32 + 16 + l16][kk * 32 + quad * 8];
      for (int ct = 0; ct < 4; ct++) {
        bf16x8 bb = *(const bf16x8*)&Bs[ct * 16 + l16][kk * 32 + quad * 8];
        acc[0][ct] = __builtin_amdgcn_mfma_f32_16x16x32_bf16(a0, bb, acc[0][ct], 0, 0, 0);
        acc[1][ct] = __builtin_amdgcn_mfma_f32_16x16x32_bf16(a1, bb, acc[1][ct], 0, 0, 0);
      }
    }
    __syncthreads();
  }
  for (int rt = 0; rt < 2; rt++)
    for (int ct = 0; ct < 4; ct++)
      for (int r = 0; r < 4; r++) {
        int s = m0 + wv * 32 + rt * 16 + quad * 4 + r;
        int n = n0 + ct * 16 + l16;
        out[(size_t)s * ND + n] = acc[rt][ct][r] + bo[n];
      }
}

extern "C" void kernel_launch(void* const* d_in, const int* in_sizes, int n_in,
                              void* d_out, int out_size, void* d_ws, size_t ws_size,
                              hipStream_t stream) {
  const float* x  = (const float*)d_in[0];
  const float* Wq = (const float*)d_in[1];
  const float* Wk = (const float*)d_in[2];
  const float* Wv = (const float*)d_in[3];
  const float* Wo = (const float*)d_in[4];
  const float* bo = (const float*)d_in[5];
  uint16_t* ws = (uint16_t*)d_ws;

  uint16_t* wt = ws;                       // 4 * WSLAB bf16 (Wq_t, Wk_t, Wv_t, Wo_t)
  uint16_t* xb = ws + 4 * WSLAB;           // XSLAB bf16
  uint16_t* q  = xb + XSLAB;               // QSLAB each
  uint16_t* k  = q + QSLAB;
  uint16_t* v  = k + QSLAB;
  uint16_t* y  = v + QSLAB;
  uint16_t* vt = y + QSLAB;                // QSLAB (V transposed)

  k_convert_x<<<dim3(XSLAB / (256 * 8)), dim3(256), 0, stream>>>(x, xb);
  k_transpose<<<dim3(1024), dim3(256), 0, stream>>>(Wq, Wk, Wv, Wo, wt);
  k_qkv<<<dim3(NS / 128, NB * NH, 3), dim3(256), 0, stream>>>(xb, wt, q);
  k_vt<<<dim3(NS / 64, NB * NH), dim3(256), 0, stream>>>(v, vt);
  k_attn<<<dim3(16, NB * NH), dim3(256), 0, stream>>>(q, k, vt, y);
  k_proj<<<dim3(NB * NS / 128, ND / 64), dim3(256), 0, stream>>>(y, wt + 3 * WSLAB, bo, (float*)d_out);
}

// Round 8
// 356.833 us; speedup vs baseline: 1.4099x; 1.1702x over previous
//
#include <hip/hip_runtime.h>
#include <hip/hip_bf16.h>
#include <stdint.h>

#define NB 4
#define NS 2048
#define ND 1024
#define NH 16
#define NHS 64
#define NEG_BIG (-1e30f)
// 1/sqrt(HS) * log2(e): folds softmax exp->exp2 into Q scaling (exactly softmax-invariant)
#define Q_SCALE 0.18033688011112042f

typedef __bf16 bf16x8 __attribute__((ext_vector_type(8)));
typedef float floatx4 __attribute__((ext_vector_type(4)));

static constexpr size_t WSLAB = (size_t)NH * ND * NHS;        // 2^20 elems per weight mat
static constexpr size_t QSLAB = (size_t)NB * NH * NS * NHS;   // 8M elems per QKV/Y slab
static constexpr size_t XSLAB = (size_t)NB * NS * ND;         // 8M elems (x as bf16)

__device__ __forceinline__ uint16_t f2b(float f) {
    union { __hip_bfloat16 h; uint16_t u; } cv;
    cv.h = __float2bfloat16(f);
    return cv.u;
}

// async global->LDS, 16B per lane. LDS dest = wave-uniform base + lane*16.
__device__ __forceinline__ void gll16(const void* g, void* l) {
  __builtin_amdgcn_global_load_lds(
      (__attribute__((address_space(1))) void*)(uintptr_t)g,
      (__attribute__((address_space(3))) void*)(uintptr_t)l,
      16, 0, 0);
}

// ---------------- kernel A: x fp32 -> bf16 ----------------
__global__ __launch_bounds__(256) void k_convert_x(
    const float* __restrict__ x, uint16_t* __restrict__ xb) {
  size_t i0 = ((size_t)blockIdx.x * 256 + threadIdx.x) * 8;
  float4 f0 = *(const float4*)&x[i0];
  float4 f1 = *(const float4*)&x[i0 + 4];
  __align__(16) uint16_t tmp[8];
  tmp[0] = f2b(f0.x); tmp[1] = f2b(f0.y); tmp[2] = f2b(f0.z); tmp[3] = f2b(f0.w);
  tmp[4] = f2b(f1.x); tmp[5] = f2b(f1.y); tmp[6] = f2b(f1.z); tmp[7] = f2b(f1.w);
  *(uint4*)&xb[i0] = *(uint4*)tmp;
}

// ---------------- kernel 0: weight convert+transpose (LDS tiled) ----------------
// wt becomes the [3072 x 1024] B^T matrix for the fused QKV GEMM (rows n = mat*1024+h*64+e),
// plus Wo^T at wt+3*WSLAB for the output projection.
__global__ __launch_bounds__(256) void k_transpose(
    const float* __restrict__ Wq, const float* __restrict__ Wk,
    const float* __restrict__ Wv, const float* __restrict__ Wo,
    uint16_t* __restrict__ ws) {
  __shared__ __align__(16) uint16_t T[64][72];
  int bid = blockIdx.x;
  int tid = threadIdx.x;
  const float* src; uint16_t* dst;
  int srcStride, dstStride, r0, c0;
  if (bid < 768) {
    int mat = bid >> 8;
    int rem = bid & 255;
    int h = rem >> 4, dt = rem & 15;
    const float* W = (mat == 0) ? Wq : (mat == 1) ? Wk : Wv;
    src = W + (size_t)h * (ND * NHS);
    dst = ws + (size_t)mat * WSLAB + (size_t)h * (NHS * ND);
    srcStride = NHS; dstStride = ND;
    r0 = dt * 64; c0 = 0;
  } else {
    int rem = bid - 768;
    int dt = rem >> 4, et = rem & 15;
    src = Wo; dst = ws + 3 * WSLAB;
    srcStride = ND; dstStride = ND;
    r0 = dt * 64; c0 = et * 64;
  }
  for (int u = tid; u < 1024; u += 256) {
    int row = u >> 4, cq = u & 15;
    float4 f = *(const float4*)&src[(size_t)(r0 + row) * srcStride + c0 + cq * 4];
    uint16_t* p = &T[row][cq * 4];
    p[0] = f2b(f.x); p[1] = f2b(f.y); p[2] = f2b(f.z); p[3] = f2b(f.w);
  }
  __syncthreads();
  for (int u = tid; u < 512; u += 256) {
    int c = u >> 3, cg = u & 7;
    __align__(16) uint16_t tmp[8];
    for (int j = 0; j < 8; j++) tmp[j] = T[cg * 8 + j][c];
    *(uint4*)&dst[(size_t)(c0 + c) * dstStride + r0 + cg * 8] = *(uint4*)tmp;
  }
}

// ---------------- kernel 1: fused QKV GEMM, m97-style ----------------
// C[8192 x 3072] = xb[8192 x 1024] @ wt^T. grid (64, 24), block 256 (2x2 waves).
// 128x128 tile, BK=64, global_load_lds staging, unpadded LDS, acc[4][4].
__global__ __launch_bounds__(256) void k_qkv(
    const uint16_t* __restrict__ xb, const uint16_t* __restrict__ wt,
    uint16_t* __restrict__ qkv) {
  __shared__ __align__(16) uint16_t As[128 * 64];
  __shared__ __align__(16) uint16_t Bs[128 * 64];
  int m0 = blockIdx.x * 128;
  int n0 = blockIdx.y * 128;
  int tid = threadIdx.x;
  int wv = tid >> 6, lane = tid & 63, quad = lane >> 4, l16 = lane & 15;
  int wr = wv >> 1, wc = wv & 1;
  int srow = lane >> 3, scol = lane & 7;   // staging: lane -> (row in 8-group, 16B col)

  floatx4 acc[4][4];
  for (int i = 0; i < 4; i++)
    for (int j = 0; j < 4; j++) acc[i][j] = (floatx4){0.f, 0.f, 0.f, 0.f};

  for (int k0 = 0; k0 < ND; k0 += 64) {
    __syncthreads();
    for (int j = 0; j < 4; j++) {
      int rg = wv * 4 + j;          // 8-row group 0..15
      int r = rg * 8 + srow;
      gll16(&xb[(size_t)(m0 + r) * ND + k0 + scol * 8], &As[rg * 512]);
      gll16(&wt[(size_t)(n0 + r) * ND + k0 + scol * 8], &Bs[rg * 512]);
    }
    __syncthreads();
    for (int kk = 0; kk < 2; kk++) {
      bf16x8 af[4], bfr[4];
      for (int t = 0; t < 4; t++) {
        af[t]  = *(const bf16x8*)&As[(wr * 64 + t * 16 + l16) * 64 + kk * 32 + quad * 8];
        bfr[t] = *(const bf16x8*)&Bs[(wc * 64 + t * 16 + l16) * 64 + kk * 32 + quad * 8];
      }
      for (int mt = 0; mt < 4; mt++)
        for (int nt = 0; nt < 4; nt++)
          acc[mt][nt] = __builtin_amdgcn_mfma_f32_16x16x32_bf16(af[mt], bfr[nt], acc[mt][nt], 0, 0, 0);
    }
  }
  // epilogue: scatter to q/k/v slabs [B,H,S,HS]; Q pre-scaled
  int mat = n0 >> 10;               // block never straddles mats (1024 % 128 == 0)
  float scale = (mat == 0) ? Q_SCALE : 1.0f;
  uint16_t* base = qkv + (size_t)mat * QSLAB;
  for (int mt = 0; mt < 4; mt++)
    for (int nt = 0; nt < 4; nt++)
      for (int r = 0; r < 4; r++) {
        int m = m0 + wr * 64 + mt * 16 + quad * 4 + r;
        int n = (n0 & 1023) + wc * 64 + nt * 16 + l16;
        int b = m >> 11, s = m & 2047;
        int h = n >> 6, e = n & 63;
        base[((size_t)(b * 16 + h) * NS + s) * NHS + e] = f2b(acc[mt][nt][r] * scale);
      }
}

// ---------------- kernel 1b: V -> V^T ([B,H,S,HS] -> [B,H,HS,S]) ----------------
__global__ __launch_bounds__(256) void k_vt(
    const uint16_t* __restrict__ v, uint16_t* __restrict__ vt) {
  __shared__ __align__(16) uint16_t T[64][72];
  int bh = blockIdx.y;
  int s0 = blockIdx.x * 64;
  int tid = threadIdx.x;
  const uint16_t* src = v + (size_t)bh * (NS * NHS);
  uint16_t* dst = vt + (size_t)bh * (NS * NHS);
  for (int u = tid; u < 512; u += 256) {
    int row = u >> 3, cg = u & 7;
    *(uint4*)&T[row][cg * 8] =
        *(const uint4*)&src[(size_t)(s0 + row) * NHS + cg * 8];
  }
  __syncthreads();
  for (int u = tid; u < 512; u += 256) {
    int e = u >> 3, cg = u & 7;
    __align__(16) uint16_t tmp[8];
    for (int j = 0; j < 8; j++) tmp[j] = T[cg * 8 + j][e];
    *(uint4*)&dst[(size_t)e * NS + s0 + cg * 8] = *(uint4*)tmp;
  }
}

// ---------------- kernel 2: causal attention, LDS-staged K/V + static softmax ----------------
__global__ __launch_bounds__(256) void k_attn(
    const uint16_t* __restrict__ Q, const uint16_t* __restrict__ K,
    const uint16_t* __restrict__ VT, uint16_t* __restrict__ Y) {
  __shared__ __align__(16) uint16_t Ks[64][72];
  __shared__ __align__(16) uint16_t Vs[64][72];        // V^T tile: [e][key]
  __shared__ __align__(16) uint16_t Ps[4][2][16][72];  // [wave][A/B][row][col]
  int bh = blockIdx.y;
  int b = bh >> 4, h = bh & 15;
  int ta = blockIdx.x;       // 0..15
  int tb = 31 - ta;          // 16..31
  const uint16_t* Qp = Q + (size_t)bh * (NS * NHS);
  const uint16_t* Kp = K + (size_t)bh * (NS * NHS);
  const uint16_t* Vp = VT + (size_t)bh * (NS * NHS);  // [e][key]
  int tid = threadIdx.x;
  int wv = tid >> 6, lane = tid & 63, quad = lane >> 4, l16 = lane & 15;

  int rA = ta * 64 + wv * 16 + l16;
  int rB = tb * 64 + wv * 16 + l16;
  bf16x8 aqA0 = *(const bf16x8*)&Qp[(size_t)rA * NHS + quad * 8];
  bf16x8 aqA1 = *(const bf16x8*)&Qp[(size_t)rA * NHS + 32 + quad * 8];
  bf16x8 aqB0 = *(const bf16x8*)&Qp[(size_t)rB * NHS + quad * 8];
  bf16x8 aqB1 = *(const bf16x8*)&Qp[(size_t)rB * NHS + 32 + quad * 8];

  float lA[4] = {0.f, 0.f, 0.f, 0.f}, lB[4] = {0.f, 0.f, 0.f, 0.f};
  floatx4 oA[4], oB[4];
  for (int ct = 0; ct < 4; ct++) {
    oA[ct] = (floatx4){0.f, 0.f, 0.f, 0.f};
    oB[ct] = (floatx4){0.f, 0.f, 0.f, 0.f};
  }

  for (int kt = 0; kt <= tb; kt++) {
    bool doA = (kt <= ta);  // uniform across block
    __syncthreads();
    for (int u = tid; u < 512; u += 256) {
      int row = u >> 3, cg = u & 7;
      *(uint4*)&Ks[row][cg * 8] =
          *(const uint4*)&Kp[(size_t)(kt * 64 + row) * NHS + cg * 8];
    }
    for (int u = tid; u < 512; u += 256) {
      int row = u >> 3, cg = u & 7;   // row = e, cols = keys
      *(uint4*)&Vs[row][cg * 8] =
          *(const uint4*)&Vp[(size_t)row * NS + kt * 64 + cg * 8];
    }
    __syncthreads();

    floatx4 sA[4], sB[4];
    for (int ct = 0; ct < 4; ct++) {
      bf16x8 kb0 = *(const bf16x8*)&Ks[ct * 16 + l16][quad * 8];
      bf16x8 kb1 = *(const bf16x8*)&Ks[ct * 16 + l16][32 + quad * 8];
      floatx4 c = (floatx4){0.f, 0.f, 0.f, 0.f};
      c = __builtin_amdgcn_mfma_f32_16x16x32_bf16(aqB0, kb0, c, 0, 0, 0);
      c = __builtin_amdgcn_mfma_f32_16x16x32_bf16(aqB1, kb1, c, 0, 0, 0);
      sB[ct] = c;
      if (doA) {
        floatx4 d = (floatx4){0.f, 0.f, 0.f, 0.f};
        d = __builtin_amdgcn_mfma_f32_16x16x32_bf16(aqA0, kb0, d, 0, 0, 0);
        d = __builtin_amdgcn_mfma_f32_16x16x32_bf16(aqA1, kb1, d, 0, 0, 0);
        sA[ct] = d;
      }
    }
    if (kt == tb) {
      int qrb = tb * 64 + wv * 16 + quad * 4;
      for (int ct = 0; ct < 4; ct++) {
        int kg = kt * 64 + ct * 16 + l16;
        for (int r = 0; r < 4; r++)
          sB[ct][r] = (kg <= qrb + r) ? sB[ct][r] : NEG_BIG;
      }
    }
    if (doA && kt == ta) {
      int qrb = ta * 64 + wv * 16 + quad * 4;
      for (int ct = 0; ct < 4; ct++) {
        int kg = kt * 64 + ct * 16 + l16;
        for (int r = 0; r < 4; r++)
          sA[ct][r] = (kg <= qrb + r) ? sA[ct][r] : NEG_BIG;
      }
    }
    for (int ct = 0; ct < 4; ct++)
      for (int r = 0; r < 4; r++) {
        float p = __builtin_amdgcn_exp2f(sB[ct][r]);
        lB[r] += p;
        Ps[wv][1][quad * 4 + r][ct * 16 + l16] = f2b(p);
      }
    if (doA)
      for (int ct = 0; ct < 4; ct++)
        for (int r = 0; r < 4; r++) {
          float p = __builtin_amdgcn_exp2f(sA[ct][r]);
          lA[r] += p;
          Ps[wv][0][quad * 4 + r][ct * 16 + l16] = f2b(p);
        }
    bf16x8 apB0 = *(const bf16x8*)&Ps[wv][1][l16][quad * 8];
    bf16x8 apB1 = *(const bf16x8*)&Ps[wv][1][l16][32 + quad * 8];
    bf16x8 apA0, apA1;
    if (doA) {
      apA0 = *(const bf16x8*)&Ps[wv][0][l16][quad * 8];
      apA1 = *(const bf16x8*)&Ps[wv][0][l16][32 + quad * 8];
    }
    for (int ct = 0; ct < 4; ct++) {
      bf16x8 vb0 = *(const bf16x8*)&Vs[ct * 16 + l16][quad * 8];
      bf16x8 vb1 = *(const bf16x8*)&Vs[ct * 16 + l16][32 + quad * 8];
      oB[ct] = __builtin_amdgcn_mfma_f32_16x16x32_bf16(apB0, vb0, oB[ct], 0, 0, 0);
      oB[ct] = __builtin_amdgcn_mfma_f32_16x16x32_bf16(apB1, vb1, oB[ct], 0, 0, 0);
      if (doA) {
        oA[ct] = __builtin_amdgcn_mfma_f32_16x16x32_bf16(apA0, vb0, oA[ct], 0, 0, 0);
        oA[ct] = __builtin_amdgcn_mfma_f32_16x16x32_bf16(apA1, vb1, oA[ct], 0, 0, 0);
      }
    }
  }
  for (int off = 1; off < 16; off <<= 1)
    for (int r = 0; r < 4; r++) {
      lA[r] += __shfl_xor(lA[r], off, 64);
      lB[r] += __shfl_xor(lB[r], off, 64);
    }
  uint16_t* yb = Y + (size_t)b * NS * ND + (size_t)h * NHS;
  for (int ct = 0; ct < 4; ct++)
    for (int r = 0; r < 4; r++) {
      int sA_ = ta * 64 + wv * 16 + quad * 4 + r;
      int sB_ = tb * 64 + wv * 16 + quad * 4 + r;
      yb[(size_t)sA_ * ND + ct * 16 + l16] = f2b(oA[ct][r] / lA[r]);
      yb[(size_t)sB_ * ND + ct * 16 + l16] = f2b(oB[ct][r] / lB[r]);
    }
}

// ---------------- kernel 3: output projection + bias, m97-style (fp32 out) ----------------
// grid (64, 8), block 256. 128x128 tile, global_load_lds staging.
__global__ __launch_bounds__(256) void k_proj(
    const uint16_t* __restrict__ y, const uint16_t* __restrict__ wot,
    const float* __restrict__ bo, float* __restrict__ out) {
  __shared__ __align__(16) uint16_t As[128 * 64];
  __shared__ __align__(16) uint16_t Bs[128 * 64];
  int m0 = blockIdx.x * 128;
  int n0 = blockIdx.y * 128;
  int tid = threadIdx.x;
  int wv = tid >> 6, lane = tid & 63, quad = lane >> 4, l16 = lane & 15;
  int wr = wv >> 1, wc = wv & 1;
  int srow = lane >> 3, scol = lane & 7;

  floatx4 acc[4][4];
  for (int i = 0; i < 4; i++)
    for (int j = 0; j < 4; j++) acc[i][j] = (floatx4){0.f, 0.f, 0.f, 0.f};

  for (int k0 = 0; k0 < ND; k0 += 64) {
    __syncthreads();
    for (int j = 0; j < 4; j++) {
      int rg = wv * 4 + j;
      int r = rg * 8 + srow;
      gll16(&y[(size_t)(m0 + r) * ND + k0 + scol * 8], &As[rg * 512]);
      gll16(&wot[(size_t)(n0 + r) * ND + k0 + scol * 8], &Bs[rg * 512]);
    }
    __syncthreads();
    for (int kk = 0; kk < 2; kk++) {
      bf16x8 af[4], bfr[4];
      for (int t = 0; t < 4; t++) {
        af[t]  = *(const bf16x8*)&As[(wr * 64 + t * 16 + l16) * 64 + kk * 32 + quad * 8];
        bfr[t] = *(const bf16x8*)&Bs[(wc * 64 + t * 16 + l16) * 64 + kk * 32 + quad * 8];
      }
      for (int mt = 0; mt < 4; mt++)
        for (int nt = 0; nt < 4; nt++)
          acc[mt][nt] = __builtin_amdgcn_mfma_f32_16x16x32_bf16(af[mt], bfr[nt], acc[mt][nt], 0, 0, 0);
    }
  }
  for (int mt = 0; mt < 4; mt++)
    for (int nt = 0; nt < 4; nt++)
      for (int r = 0; r < 4; r++) {
        int s = m0 + wr * 64 + mt * 16 + quad * 4 + r;
        int n = n0 + wc * 64 + nt * 16 + l16;
        out[(size_t)s * ND + n] = acc[mt][nt][r] + bo[n];
      }
}

extern "C" void kernel_launch(void* const* d_in, const int* in_sizes, int n_in,
                              void* d_out, int out_size, void* d_ws, size_t ws_size,
                              hipStream_t stream) {
  const float* x  = (const float*)d_in[0];
  const float* Wq = (const float*)d_in[1];
  const float* Wk = (const float*)d_in[2];
  const float* Wv = (const float*)d_in[3];
  const float* Wo = (const float*)d_in[4];
  const float* bo = (const float*)d_in[5];
  uint16_t* ws = (uint16_t*)d_ws;

  uint16_t* wt = ws;                       // 4 * WSLAB bf16 (Wq_t, Wk_t, Wv_t, Wo_t)
  uint16_t* xb = ws + 4 * WSLAB;           // XSLAB bf16
  uint16_t* q  = xb + XSLAB;               // QSLAB each
  uint16_t* k  = q + QSLAB;
  uint16_t* v  = k + QSLAB;
  uint16_t* y  = v + QSLAB;
  uint16_t* vt = y + QSLAB;                // QSLAB (V transposed)

  k_convert_x<<<dim3(XSLAB / (256 * 8)), dim3(256), 0, stream>>>(x, xb);
  k_transpose<<<dim3(1024), dim3(256), 0, stream>>>(Wq, Wk, Wv, Wo, wt);
  k_qkv<<<dim3(64, 24), dim3(256), 0, stream>>>(xb, wt, q);
  k_vt<<<dim3(NS / 64, NB * NH), dim3(256), 0, stream>>>(v, vt);
  k_attn<<<dim3(16, NB * NH), dim3(256), 0, stream>>>(q, k, vt, y);
  k_proj<<<dim3(64, 8), dim3(256), 0, stream>>>(y, wt + 3 * WSLAB, bo, (float*)d_out);
}

// Round 9
// 307.034 us; speedup vs baseline: 1.6386x; 1.1622x over previous
//
#include <hip/hip_runtime.h>
#include <hip/hip_bf16.h>
#include <stdint.h>

#define NB 4
#define NS 2048
#define ND 1024
#define NH 16
#define NHS 64
#define NEG_BIG (-1e30f)
// 1/sqrt(HS) * log2(e): folds softmax exp->exp2 into Q scaling (exactly softmax-invariant)
#define Q_SCALE 0.18033688011112042f

typedef __bf16 bf16x8 __attribute__((ext_vector_type(8)));
typedef float floatx4 __attribute__((ext_vector_type(4)));
typedef short s16x4 __attribute__((ext_vector_type(4)));

#if defined(__has_builtin)
#if __has_builtin(__builtin_amdgcn_mfma_f32_16x16x16bf16_1k)
#define HAVE_MFMA1K 1
#endif
#endif
#ifndef HAVE_MFMA1K
#define HAVE_MFMA1K 0
#endif

static constexpr size_t WSLAB = (size_t)NH * ND * NHS;        // 2^20 elems per weight mat
static constexpr size_t QSLAB = (size_t)NB * NH * NS * NHS;   // 8M elems per QKV/Y slab
static constexpr size_t XSLAB = (size_t)NB * NS * ND;         // 8M elems (x as bf16)

__device__ __forceinline__ uint16_t f2b(float f) {
    union { __hip_bfloat16 h; uint16_t u; } cv;
    cv.h = __float2bfloat16(f);
    return cv.u;
}

// async global->LDS, 16B per lane. LDS dest = wave-uniform base + lane*16; per-lane 16B-contiguous src.
__device__ __forceinline__ void gll16(const void* g, void* l) {
  __builtin_amdgcn_global_load_lds(
      (__attribute__((address_space(1))) void*)(uintptr_t)g,
      (__attribute__((address_space(3))) void*)(uintptr_t)l,
      16, 0, 0);
}

// ---------------- kernel A: x fp32 -> bf16 ----------------
__global__ __launch_bounds__(256) void k_convert_x(
    const float* __restrict__ x, uint16_t* __restrict__ xb) {
  size_t i0 = ((size_t)blockIdx.x * 256 + threadIdx.x) * 8;
  float4 f0 = *(const float4*)&x[i0];
  float4 f1 = *(const float4*)&x[i0 + 4];
  __align__(16) uint16_t tmp[8];
  tmp[0] = f2b(f0.x); tmp[1] = f2b(f0.y); tmp[2] = f2b(f0.z); tmp[3] = f2b(f0.w);
  tmp[4] = f2b(f1.x); tmp[5] = f2b(f1.y); tmp[6] = f2b(f1.z); tmp[7] = f2b(f1.w);
  *(uint4*)&xb[i0] = *(uint4*)tmp;
}

// ---------------- kernel 0: weight convert+transpose (LDS tiled) ----------------
__global__ __launch_bounds__(256) void k_transpose(
    const float* __restrict__ Wq, const float* __restrict__ Wk,
    const float* __restrict__ Wv, const float* __restrict__ Wo,
    uint16_t* __restrict__ ws) {
  __shared__ __align__(16) uint16_t T[64][72];
  int bid = blockIdx.x;
  int tid = threadIdx.x;
  const float* src; uint16_t* dst;
  int srcStride, dstStride, r0, c0;
  if (bid < 768) {
    int mat = bid >> 8;
    int rem = bid & 255;
    int h = rem >> 4, dt = rem & 15;
    const float* W = (mat == 0) ? Wq : (mat == 1) ? Wk : Wv;
    src = W + (size_t)h * (ND * NHS);
    dst = ws + (size_t)mat * WSLAB + (size_t)h * (NHS * ND);
    srcStride = NHS; dstStride = ND;
    r0 = dt * 64; c0 = 0;
  } else {
    int rem = bid - 768;
    int dt = rem >> 4, et = rem & 15;
    src = Wo; dst = ws + 3 * WSLAB;
    srcStride = ND; dstStride = ND;
    r0 = dt * 64; c0 = et * 64;
  }
  for (int u = tid; u < 1024; u += 256) {
    int row = u >> 4, cq = u & 15;
    float4 f = *(const float4*)&src[(size_t)(r0 + row) * srcStride + c0 + cq * 4];
    uint16_t* p = &T[row][cq * 4];
    p[0] = f2b(f.x); p[1] = f2b(f.y); p[2] = f2b(f.z); p[3] = f2b(f.w);
  }
  __syncthreads();
  for (int u = tid; u < 512; u += 256) {
    int c = u >> 3, cg = u & 7;
    __align__(16) uint16_t tmp[8];
    for (int j = 0; j < 8; j++) tmp[j] = T[cg * 8 + j][c];
    *(uint4*)&dst[(size_t)(c0 + c) * dstStride + r0 + cg * 8] = *(uint4*)tmp;
  }
}

// ---------------- kernel 1: fused QKV GEMM, m97-style ----------------
__global__ __launch_bounds__(256) void k_qkv(
    const uint16_t* __restrict__ xb, const uint16_t* __restrict__ wt,
    uint16_t* __restrict__ qkv) {
  __shared__ __align__(16) uint16_t As[128 * 64];
  __shared__ __align__(16) uint16_t Bs[128 * 64];
  int m0 = blockIdx.x * 128;
  int n0 = blockIdx.y * 128;
  int tid = threadIdx.x;
  int wv = tid >> 6, lane = tid & 63, quad = lane >> 4, l16 = lane & 15;
  int wr = wv >> 1, wc = wv & 1;
  int srow = lane >> 3, scol = lane & 7;

  floatx4 acc[4][4];
  for (int i = 0; i < 4; i++)
    for (int j = 0; j < 4; j++) acc[i][j] = (floatx4){0.f, 0.f, 0.f, 0.f};

  for (int k0 = 0; k0 < ND; k0 += 64) {
    __syncthreads();
    for (int j = 0; j < 4; j++) {
      int rg = wv * 4 + j;
      int r = rg * 8 + srow;
      gll16(&xb[(size_t)(m0 + r) * ND + k0 + scol * 8], &As[rg * 512]);
      gll16(&wt[(size_t)(n0 + r) * ND + k0 + scol * 8], &Bs[rg * 512]);
    }
    __syncthreads();
    for (int kk = 0; kk < 2; kk++) {
      bf16x8 af[4], bfr[4];
      for (int t = 0; t < 4; t++) {
        af[t]  = *(const bf16x8*)&As[(wr * 64 + t * 16 + l16) * 64 + kk * 32 + quad * 8];
        bfr[t] = *(const bf16x8*)&Bs[(wc * 64 + t * 16 + l16) * 64 + kk * 32 + quad * 8];
      }
      for (int mt = 0; mt < 4; mt++)
        for (int nt = 0; nt < 4; nt++)
          acc[mt][nt] = __builtin_amdgcn_mfma_f32_16x16x32_bf16(af[mt], bfr[nt], acc[mt][nt], 0, 0, 0);
    }
  }
  int mat = n0 >> 10;
  float scale = (mat == 0) ? Q_SCALE : 1.0f;
  uint16_t* base = qkv + (size_t)mat * QSLAB;
  for (int mt = 0; mt < 4; mt++)
    for (int nt = 0; nt < 4; nt++)
      for (int r = 0; r < 4; r++) {
        int m = m0 + wr * 64 + mt * 16 + quad * 4 + r;
        int n = (n0 & 1023) + wc * 64 + nt * 16 + l16;
        int b = m >> 11, s = m & 2047;
        int h = n >> 6, e = n & 63;
        base[((size_t)(b * 16 + h) * NS + s) * NHS + e] = f2b(acc[mt][nt][r] * scale);
      }
}

// ---------------- kernel 1b: V -> V^T ([B,H,S,HS] -> [B,H,HS,S]) ----------------
__global__ __launch_bounds__(256) void k_vt(
    const uint16_t* __restrict__ v, uint16_t* __restrict__ vt) {
  __shared__ __align__(16) uint16_t T[64][72];
  int bh = blockIdx.y;
  int s0 = blockIdx.x * 64;
  int tid = threadIdx.x;
  const uint16_t* src = v + (size_t)bh * (NS * NHS);
  uint16_t* dst = vt + (size_t)bh * (NS * NHS);
  for (int u = tid; u < 512; u += 256) {
    int row = u >> 3, cg = u & 7;
    *(uint4*)&T[row][cg * 8] =
        *(const uint4*)&src[(size_t)(s0 + row) * NHS + cg * 8];
  }
  __syncthreads();
  for (int u = tid; u < 512; u += 256) {
    int e = u >> 3, cg = u & 7;
    __align__(16) uint16_t tmp[8];
    for (int j = 0; j < 8; j++) tmp[j] = T[cg * 8 + j][e];
    *(uint4*)&dst[(size_t)e * NS + s0 + cg * 8] = *(uint4*)tmp;
  }
}

#if HAVE_MFMA1K
// ---------------- kernel 2: causal attention, S^T trick (no P LDS round-trip) ----------------
// S^T = K.Q^T puts P^T directly in the B-operand layout of 16x16x16 MFMA;
// O^T = V^T.P^T accumulates in registers. gll16-staged K/V^T tiles (unpadded).
__global__ __launch_bounds__(256, 4) void k_attn(
    const uint16_t* __restrict__ Q, const uint16_t* __restrict__ K,
    const uint16_t* __restrict__ VT, uint16_t* __restrict__ Y) {
  __shared__ __align__(16) uint16_t Ks[64 * 64];   // [key][e]
  __shared__ __align__(16) uint16_t Vs[64 * 64];   // [e][key]
  int bh = blockIdx.y;
  int b = bh >> 4, h = bh & 15;
  int ta = blockIdx.x;       // 0..15
  int tb = 31 - ta;          // 16..31
  const uint16_t* Qp = Q + (size_t)bh * (NS * NHS);
  const uint16_t* Kp = K + (size_t)bh * (NS * NHS);
  const uint16_t* Vp = VT + (size_t)bh * (NS * NHS);  // [e][key]
  int tid = threadIdx.x;
  int wv = tid >> 6, lane = tid & 63, quad = lane >> 4, l16 = lane & 15;
  int srow = lane >> 3, scol = lane & 7;

  // Q fragments from global; used as B operand of S^T = K.Q^T (n = q-row = l16)
  int rA = ta * 64 + wv * 16 + l16;
  int rB = tb * 64 + wv * 16 + l16;
  bf16x8 aqA0 = *(const bf16x8*)&Qp[(size_t)rA * NHS + quad * 8];
  bf16x8 aqA1 = *(const bf16x8*)&Qp[(size_t)rA * NHS + 32 + quad * 8];
  bf16x8 aqB0 = *(const bf16x8*)&Qp[(size_t)rB * NHS + quad * 8];
  bf16x8 aqB1 = *(const bf16x8*)&Qp[(size_t)rB * NHS + 32 + quad * 8];

  float lAs = 0.f, lBs = 0.f;          // per-lane row-sum (all p of a lane share q-row l16)
  floatx4 oA[4], oB[4];                // O^T accumulators, one per e-tile
  for (int et = 0; et < 4; et++) {
    oA[et] = (floatx4){0.f, 0.f, 0.f, 0.f};
    oB[et] = (floatx4){0.f, 0.f, 0.f, 0.f};
  }

  for (int kt = 0; kt <= tb; kt++) {
    bool doA = (kt <= ta);  // uniform across block
    __syncthreads();
    for (int j = 0; j < 2; j++) {
      int rg = wv * 2 + j;  // 8-row group 0..7
      gll16(&Kp[(size_t)(kt * 64 + rg * 8 + srow) * NHS + scol * 8], &Ks[rg * 512]);
      gll16(&Vp[(size_t)(rg * 8 + srow) * NS + kt * 64 + scol * 8], &Vs[rg * 512]);
    }
    __syncthreads();

    // ---- S^T tiles + mask + exp2 + pack (P^T in B-layout of K=16 MFMA) ----
    s16x4 pbA[4], pbB[4];
    for (int ct = 0; ct < 4; ct++) {
      bf16x8 kb0 = *(const bf16x8*)&Ks[(ct * 16 + l16) * 64 + quad * 8];
      bf16x8 kb1 = *(const bf16x8*)&Ks[(ct * 16 + l16) * 64 + 32 + quad * 8];
      int key = kt * 64 + ct * 16 + quad * 4;
      floatx4 c = (floatx4){0.f, 0.f, 0.f, 0.f};
      c = __builtin_amdgcn_mfma_f32_16x16x32_bf16(kb0, aqB0, c, 0, 0, 0);
      c = __builtin_amdgcn_mfma_f32_16x16x32_bf16(kb1, aqB1, c, 0, 0, 0);
      for (int r = 0; r < 4; r++) {
        float s = (kt == tb && key + r > rB) ? NEG_BIG : c[r];
        float p = __builtin_amdgcn_exp2f(s);
        lBs += p;
        pbB[ct][r] = (short)f2b(p);
      }
      if (doA) {
        floatx4 d = (floatx4){0.f, 0.f, 0.f, 0.f};
        d = __builtin_amdgcn_mfma_f32_16x16x32_bf16(kb0, aqA0, d, 0, 0, 0);
        d = __builtin_amdgcn_mfma_f32_16x16x32_bf16(kb1, aqA1, d, 0, 0, 0);
        for (int r = 0; r < 4; r++) {
          float s = (kt == ta && key + r > rA) ? NEG_BIG : d[r];
          float p = __builtin_amdgcn_exp2f(s);
          lAs += p;
          pbA[ct][r] = (short)f2b(p);
        }
      }
    }
    // ---- O^T += V^T . P^T (A-frag = 4 keys of V^T via ds_read_b64, shared A/B) ----
    for (int et = 0; et < 4; et++)
      for (int ct = 0; ct < 4; ct++) {
        s16x4 va = *(const s16x4*)&Vs[(et * 16 + l16) * 64 + ct * 16 + quad * 4];
        oB[et] = __builtin_amdgcn_mfma_f32_16x16x16bf16_1k(va, pbB[ct], oB[et], 0, 0, 0);
        if (doA)
          oA[et] = __builtin_amdgcn_mfma_f32_16x16x16bf16_1k(va, pbA[ct], oA[et], 0, 0, 0);
      }
  }
  // ---- reduce row-sums across the 4 quads, normalize, packed store ----
  lAs += __shfl_xor(lAs, 16, 64); lAs += __shfl_xor(lAs, 32, 64);
  lBs += __shfl_xor(lBs, 16, 64); lBs += __shfl_xor(lBs, 32, 64);
  float invA = 1.f / lAs, invB = 1.f / lBs;
  uint16_t* yb = Y + (size_t)b * NS * ND + (size_t)h * NHS;
  for (int et = 0; et < 4; et++) {
    __align__(8) uint16_t tA[4], tB[4];
    for (int r = 0; r < 4; r++) {
      tA[r] = f2b(oA[et][r] * invA);
      tB[r] = f2b(oB[et][r] * invB);
    }
    *(uint2*)&yb[(size_t)rA * ND + et * 16 + quad * 4] = *(uint2*)tA;
    *(uint2*)&yb[(size_t)rB * ND + et * 16 + quad * 4] = *(uint2*)tB;
  }
}
#else
// ---------------- fallback: round-8 k_attn (LDS-staged K/V + P round-trip) ----------------
__global__ __launch_bounds__(256) void k_attn(
    const uint16_t* __restrict__ Q, const uint16_t* __restrict__ K,
    const uint16_t* __restrict__ VT, uint16_t* __restrict__ Y) {
  __shared__ __align__(16) uint16_t Ks[64][72];
  __shared__ __align__(16) uint16_t Vs[64][72];
  __shared__ __align__(16) uint16_t Ps[4][2][16][72];
  int bh = blockIdx.y;
  int b = bh >> 4, h = bh & 15;
  int ta = blockIdx.x;
  int tb = 31 - ta;
  const uint16_t* Qp = Q + (size_t)bh * (NS * NHS);
  const uint16_t* Kp = K + (size_t)bh * (NS * NHS);
  const uint16_t* Vp = VT + (size_t)bh * (NS * NHS);
  int tid = threadIdx.x;
  int wv = tid >> 6, lane = tid & 63, quad = lane >> 4, l16 = lane & 15;

  int rA = ta * 64 + wv * 16 + l16;
  int rB = tb * 64 + wv * 16 + l16;
  bf16x8 aqA0 = *(const bf16x8*)&Qp[(size_t)rA * NHS + quad * 8];
  bf16x8 aqA1 = *(const bf16x8*)&Qp[(size_t)rA * NHS + 32 + quad * 8];
  bf16x8 aqB0 = *(const bf16x8*)&Qp[(size_t)rB * NHS + quad * 8];
  bf16x8 aqB1 = *(const bf16x8*)&Qp[(size_t)rB * NHS + 32 + quad * 8];

  float lA[4] = {0.f, 0.f, 0.f, 0.f}, lB[4] = {0.f, 0.f, 0.f, 0.f};
  floatx4 oA[4], oB[4];
  for (int ct = 0; ct < 4; ct++) {
    oA[ct] = (floatx4){0.f, 0.f, 0.f, 0.f};
    oB[ct] = (floatx4){0.f, 0.f, 0.f, 0.f};
  }
  for (int kt = 0; kt <= tb; kt++) {
    bool doA = (kt <= ta);
    __syncthreads();
    for (int u = tid; u < 512; u += 256) {
      int row = u >> 3, cg = u & 7;
      *(uint4*)&Ks[row][cg * 8] =
          *(const uint4*)&Kp[(size_t)(kt * 64 + row) * NHS + cg * 8];
    }
    for (int u = tid; u < 512; u += 256) {
      int row = u >> 3, cg = u & 7;
      *(uint4*)&Vs[row][cg * 8] =
          *(const uint4*)&Vp[(size_t)row * NS + kt * 64 + cg * 8];
    }
    __syncthreads();
    floatx4 sA[4], sB[4];
    for (int ct = 0; ct < 4; ct++) {
      bf16x8 kb0 = *(const bf16x8*)&Ks[ct * 16 + l16][quad * 8];
      bf16x8 kb1 = *(const bf16x8*)&Ks[ct * 16 + l16][32 + quad * 8];
      floatx4 c = (floatx4){0.f, 0.f, 0.f, 0.f};
      c = __builtin_amdgcn_mfma_f32_16x16x32_bf16(aqB0, kb0, c, 0, 0, 0);
      c = __builtin_amdgcn_mfma_f32_16x16x32_bf16(aqB1, kb1, c, 0, 0, 0);
      sB[ct] = c;
      if (doA) {
        floatx4 d = (floatx4){0.f, 0.f, 0.f, 0.f};
        d = __builtin_amdgcn_mfma_f32_16x16x32_bf16(aqA0, kb0, d, 0, 0, 0);
        d = __builtin_amdgcn_mfma_f32_16x16x32_bf16(aqA1, kb1, d, 0, 0, 0);
        sA[ct] = d;
      }
    }
    if (kt == tb) {
      int qrb = tb * 64 + wv * 16 + quad * 4;
      for (int ct = 0; ct < 4; ct++) {
        int kg = kt * 64 + ct * 16 + l16;
        for (int r = 0; r < 4; r++)
          sB[ct][r] = (kg <= qrb + r) ? sB[ct][r] : NEG_BIG;
      }
    }
    if (doA && kt == ta) {
      int qrb = ta * 64 + wv * 16 + quad * 4;
      for (int ct = 0; ct < 4; ct++) {
        int kg = kt * 64 + ct * 16 + l16;
        for (int r = 0; r < 4; r++)
          sA[ct][r] = (kg <= qrb + r) ? sA[ct][r] : NEG_BIG;
      }
    }
    for (int ct = 0; ct < 4; ct++)
      for (int r = 0; r < 4; r++) {
        float p = __builtin_amdgcn_exp2f(sB[ct][r]);
        lB[r] += p;
        Ps[wv][1][quad * 4 + r][ct * 16 + l16] = f2b(p);
      }
    if (doA)
      for (int ct = 0; ct < 4; ct++)
        for (int r = 0; r < 4; r++) {
          float p = __builtin_amdgcn_exp2f(sA[ct][r]);
          lA[r] += p;
          Ps[wv][0][quad * 4 + r][ct * 16 + l16] = f2b(p);
        }
    bf16x8 apB0 = *(const bf16x8*)&Ps[wv][1][l16][quad * 8];
    bf16x8 apB1 = *(const bf16x8*)&Ps[wv][1][l16][32 + quad * 8];
    bf16x8 apA0, apA1;
    if (doA) {
      apA0 = *(const bf16x8*)&Ps[wv][0][l16][quad * 8];
      apA1 = *(const bf16x8*)&Ps[wv][0][l16][32 + quad * 8];
    }
    for (int ct = 0; ct < 4; ct++) {
      bf16x8 vb0 = *(const bf16x8*)&Vs[ct * 16 + l16][quad * 8];
      bf16x8 vb1 = *(const bf16x8*)&Vs[ct * 16 + l16][32 + quad * 8];
      oB[ct] = __builtin_amdgcn_mfma_f32_16x16x32_bf16(apB0, vb0, oB[ct], 0, 0, 0);
      oB[ct] = __builtin_amdgcn_mfma_f32_16x16x32_bf16(apB1, vb1, oB[ct], 0, 0, 0);
      if (doA) {
        oA[ct] = __builtin_amdgcn_mfma_f32_16x16x32_bf16(apA0, vb0, oA[ct], 0, 0, 0);
        oA[ct] = __builtin_amdgcn_mfma_f32_16x16x32_bf16(apA1, vb1, oA[ct], 0, 0, 0);
      }
    }
  }
  for (int off = 1; off < 16; off <<= 1)
    for (int r = 0; r < 4; r++) {
      lA[r] += __shfl_xor(lA[r], off, 64);
      lB[r] += __shfl_xor(lB[r], off, 64);
    }
  uint16_t* yb = Y + (size_t)b * NS * ND + (size_t)h * NHS;
  for (int ct = 0; ct < 4; ct++)
    for (int r = 0; r < 4; r++) {
      int sA_ = ta * 64 + wv * 16 + quad * 4 + r;
      int sB_ = tb * 64 + wv * 16 + quad * 4 + r;
      yb[(size_t)sA_ * ND + ct * 16 + l16] = f2b(oA[ct][r] / lA[r]);
      yb[(size_t)sB_ * ND + ct * 16 + l16] = f2b(oB[ct][r] / lB[r]);
    }
}
#endif

// ---------------- kernel 3: output projection + bias, m97-style (fp32 out) ----------------
__global__ __launch_bounds__(256) void k_proj(
    const uint16_t* __restrict__ y, const uint16_t* __restrict__ wot,
    const float* __restrict__ bo, float* __restrict__ out) {
  __shared__ __align__(16) uint16_t As[128 * 64];
  __shared__ __align__(16) uint16_t Bs[128 * 64];
  int m0 = blockIdx.x * 128;
  int n0 = blockIdx.y * 128;
  int tid = threadIdx.x;
  int wv = tid >> 6, lane = tid & 63, quad = lane >> 4, l16 = lane & 15;
  int wr = wv >> 1, wc = wv & 1;
  int srow = lane >> 3, scol = lane & 7;

  floatx4 acc[4][4];
  for (int i = 0; i < 4; i++)
    for (int j = 0; j < 4; j++) acc[i][j] = (floatx4){0.f, 0.f, 0.f, 0.f};

  for (int k0 = 0; k0 < ND; k0 += 64) {
    __syncthreads();
    for (int j = 0; j < 4; j++) {
      int rg = wv * 4 + j;
      int r = rg * 8 + srow;
      gll16(&y[(size_t)(m0 + r) * ND + k0 + scol * 8], &As[rg * 512]);
      gll16(&wot[(size_t)(n0 + r) * ND + k0 + scol * 8], &Bs[rg * 512]);
    }
    __syncthreads();
    for (int kk = 0; kk < 2; kk++) {
      bf16x8 af[4], bfr[4];
      for (int t = 0; t < 4; t++) {
        af[t]  = *(const bf16x8*)&As[(wr * 64 + t * 16 + l16) * 64 + kk * 32 + quad * 8];
        bfr[t] = *(const bf16x8*)&Bs[(wc * 64 + t * 16 + l16) * 64 + kk * 32 + quad * 8];
      }
      for (int mt = 0; mt < 4; mt++)
        for (int nt = 0; nt < 4; nt++)
          acc[mt][nt] = __builtin_amdgcn_mfma_f32_16x16x32_bf16(af[mt], bfr[nt], acc[mt][nt], 0, 0, 0);
    }
  }
  for (int mt = 0; mt < 4; mt++)
    for (int nt = 0; nt < 4; nt++)
      for (int r = 0; r < 4; r++) {
        int s = m0 + wr * 64 + mt * 16 + quad * 4 + r;
        int n = n0 + wc * 64 + nt * 16 + l16;
        out[(size_t)s * ND + n] = acc[mt][nt][r] + bo[n];
      }
}

extern "C" void kernel_launch(void* const* d_in, const int* in_sizes, int n_in,
                              void* d_out, int out_size, void* d_ws, size_t ws_size,
                              hipStream_t stream) {
  const float* x  = (const float*)d_in[0];
  const float* Wq = (const float*)d_in[1];
  const float* Wk = (const float*)d_in[2];
  const float* Wv = (const float*)d_in[3];
  const float* Wo = (const float*)d_in[4];
  const float* bo = (const float*)d_in[5];
  uint16_t* ws = (uint16_t*)d_ws;

  uint16_t* wt = ws;                       // 4 * WSLAB bf16 (Wq_t, Wk_t, Wv_t, Wo_t)
  uint16_t* xb = ws + 4 * WSLAB;           // XSLAB bf16
  uint16_t* q  = xb + XSLAB;               // QSLAB each
  uint16_t* k  = q + QSLAB;
  uint16_t* v  = k + QSLAB;
  uint16_t* y  = v + QSLAB;
  uint16_t* vt = y + QSLAB;                // QSLAB (V transposed)

  k_convert_x<<<dim3(XSLAB / (256 * 8)), dim3(256), 0, stream>>>(x, xb);
  k_transpose<<<dim3(1024), dim3(256), 0, stream>>>(Wq, Wk, Wv, Wo, wt);
  k_qkv<<<dim3(64, 24), dim3(256), 0, stream>>>(xb, wt, q);
  k_vt<<<dim3(NS / 64, NB * NH), dim3(256), 0, stream>>>(v, vt);
  k_attn<<<dim3(16, NB * NH), dim3(256), 0, stream>>>(q, k, vt, y);
  k_proj<<<dim3(64, 8), dim3(256), 0, stream>>>(y, wt + 3 * WSLAB, bo, (float*)d_out);
}

// Round 10
// 306.562 us; speedup vs baseline: 1.6411x; 1.0015x over previous
//
#include <hip/hip_runtime.h>
#include <hip/hip_bf16.h>
#include <stdint.h>

#define NB 4
#define NS 2048
#define ND 1024
#define NH 16
#define NHS 64
#define NEG_BIG (-1e30f)
// 1/sqrt(HS) * log2(e): folds softmax exp->exp2 into Q scaling (exactly softmax-invariant)
#define Q_SCALE 0.18033688011112042f

typedef __bf16 bf16x8 __attribute__((ext_vector_type(8)));
typedef float floatx4 __attribute__((ext_vector_type(4)));
typedef short s16x4 __attribute__((ext_vector_type(4)));

#if defined(__has_builtin)
#if __has_builtin(__builtin_amdgcn_mfma_f32_16x16x16bf16_1k)
#define HAVE_MFMA1K 1
#endif
#endif
#ifndef HAVE_MFMA1K
#define HAVE_MFMA1K 0
#endif

static constexpr size_t WSLAB = (size_t)NH * ND * NHS;        // 2^20 elems per weight mat
static constexpr size_t QSLAB = (size_t)NB * NH * NS * NHS;   // 8M elems per QKV/Y slab
static constexpr size_t XSLAB = (size_t)NB * NS * ND;         // 8M elems (x as bf16)

__device__ __forceinline__ uint16_t f2b(float f) {
    union { __hip_bfloat16 h; uint16_t u; } cv;
    cv.h = __float2bfloat16(f);
    return cv.u;
}

// async global->LDS, 16B per lane. LDS dest = wave-uniform base + lane*16 (UNPADDED only).
__device__ __forceinline__ void gll16(const void* g, void* l) {
  __builtin_amdgcn_global_load_lds(
      (__attribute__((address_space(1))) void*)(uintptr_t)g,
      (__attribute__((address_space(3))) void*)(uintptr_t)l,
      16, 0, 0);
}

// ---------------- kernel P: merged x-convert + weight convert/transpose ----------------
// blocks 0..4095: x fp32->bf16 (2048 elems each). blocks 4096..5119: weight transpose.
__global__ __launch_bounds__(256) void k_prep(
    const float* __restrict__ x, const float* __restrict__ Wq,
    const float* __restrict__ Wk, const float* __restrict__ Wv,
    const float* __restrict__ Wo, uint16_t* __restrict__ xb,
    uint16_t* __restrict__ wt) {
  __shared__ __align__(16) uint16_t T[64][72];
  int bid = blockIdx.x;
  int tid = threadIdx.x;
  if (bid < 4096) {
    size_t i0 = ((size_t)bid * 256 + tid) * 8;
    float4 f0 = *(const float4*)&x[i0];
    float4 f1 = *(const float4*)&x[i0 + 4];
    __align__(16) uint16_t tmp[8];
    tmp[0] = f2b(f0.x); tmp[1] = f2b(f0.y); tmp[2] = f2b(f0.z); tmp[3] = f2b(f0.w);
    tmp[4] = f2b(f1.x); tmp[5] = f2b(f1.y); tmp[6] = f2b(f1.z); tmp[7] = f2b(f1.w);
    *(uint4*)&xb[i0] = *(uint4*)tmp;
    return;
  }
  bid -= 4096;
  const float* src; uint16_t* dst;
  int srcStride, dstStride, r0, c0;
  if (bid < 768) {
    int mat = bid >> 8;
    int rem = bid & 255;
    int h = rem >> 4, dt = rem & 15;
    const float* W = (mat == 0) ? Wq : (mat == 1) ? Wk : Wv;
    src = W + (size_t)h * (ND * NHS);
    dst = wt + (size_t)mat * WSLAB + (size_t)h * (NHS * ND);
    srcStride = NHS; dstStride = ND;
    r0 = dt * 64; c0 = 0;
  } else {
    int rem = bid - 768;
    int dt = rem >> 4, et = rem & 15;
    src = Wo; dst = wt + 3 * WSLAB;
    srcStride = ND; dstStride = ND;
    r0 = dt * 64; c0 = et * 64;
  }
  for (int u = tid; u < 1024; u += 256) {
    int row = u >> 4, cq = u & 15;
    float4 f = *(const float4*)&src[(size_t)(r0 + row) * srcStride + c0 + cq * 4];
    uint16_t* p = &T[row][cq * 4];
    p[0] = f2b(f.x); p[1] = f2b(f.y); p[2] = f2b(f.z); p[3] = f2b(f.w);
  }
  __syncthreads();
  for (int u = tid; u < 512; u += 256) {
    int c = u >> 3, cg = u & 7;
    __align__(16) uint16_t tmp[8];
    for (int j = 0; j < 8; j++) tmp[j] = T[cg * 8 + j][c];
    *(uint4*)&dst[(size_t)(c0 + c) * dstStride + r0 + cg * 8] = *(uint4*)tmp;
  }
}

// ---------------- kernel 1: fused QKV GEMM, m97-style ----------------
__global__ __launch_bounds__(256) void k_qkv(
    const uint16_t* __restrict__ xb, const uint16_t* __restrict__ wt,
    uint16_t* __restrict__ qkv) {
  __shared__ __align__(16) uint16_t As[128 * 64];
  __shared__ __align__(16) uint16_t Bs[128 * 64];
  int m0 = blockIdx.x * 128;
  int n0 = blockIdx.y * 128;
  int tid = threadIdx.x;
  int wv = tid >> 6, lane = tid & 63, quad = lane >> 4, l16 = lane & 15;
  int wr = wv >> 1, wc = wv & 1;
  int srow = lane >> 3, scol = lane & 7;

  floatx4 acc[4][4];
  for (int i = 0; i < 4; i++)
    for (int j = 0; j < 4; j++) acc[i][j] = (floatx4){0.f, 0.f, 0.f, 0.f};

  for (int k0 = 0; k0 < ND; k0 += 64) {
    __syncthreads();
    for (int j = 0; j < 4; j++) {
      int rg = wv * 4 + j;
      int r = rg * 8 + srow;
      gll16(&xb[(size_t)(m0 + r) * ND + k0 + scol * 8], &As[rg * 512]);
      gll16(&wt[(size_t)(n0 + r) * ND + k0 + scol * 8], &Bs[rg * 512]);
    }
    __syncthreads();
    for (int kk = 0; kk < 2; kk++) {
      bf16x8 af[4], bfr[4];
      for (int t = 0; t < 4; t++) {
        af[t]  = *(const bf16x8*)&As[(wr * 64 + t * 16 + l16) * 64 + kk * 32 + quad * 8];
        bfr[t] = *(const bf16x8*)&Bs[(wc * 64 + t * 16 + l16) * 64 + kk * 32 + quad * 8];
      }
      for (int mt = 0; mt < 4; mt++)
        for (int nt = 0; nt < 4; nt++)
          acc[mt][nt] = __builtin_amdgcn_mfma_f32_16x16x32_bf16(af[mt], bfr[nt], acc[mt][nt], 0, 0, 0);
    }
  }
  int mat = n0 >> 10;
  float scale = (mat == 0) ? Q_SCALE : 1.0f;
  uint16_t* base = qkv + (size_t)mat * QSLAB;
  for (int mt = 0; mt < 4; mt++)
    for (int nt = 0; nt < 4; nt++)
      for (int r = 0; r < 4; r++) {
        int m = m0 + wr * 64 + mt * 16 + quad * 4 + r;
        int n = (n0 & 1023) + wc * 64 + nt * 16 + l16;
        int b = m >> 11, s = m & 2047;
        int h = n >> 6, e = n & 63;
        base[((size_t)(b * 16 + h) * NS + s) * NHS + e] = f2b(acc[mt][nt][r] * scale);
      }
}

// ---------------- kernel 1b: V -> V^T ([B,H,S,HS] -> [B,H,HS,S]) ----------------
__global__ __launch_bounds__(256) void k_vt(
    const uint16_t* __restrict__ v, uint16_t* __restrict__ vt) {
  __shared__ __align__(16) uint16_t T[64][72];
  int bh = blockIdx.y;
  int s0 = blockIdx.x * 64;
  int tid = threadIdx.x;
  const uint16_t* src = v + (size_t)bh * (NS * NHS);
  uint16_t* dst = vt + (size_t)bh * (NS * NHS);
  for (int u = tid; u < 512; u += 256) {
    int row = u >> 3, cg = u & 7;
    *(uint4*)&T[row][cg * 8] =
        *(const uint4*)&src[(size_t)(s0 + row) * NHS + cg * 8];
  }
  __syncthreads();
  for (int u = tid; u < 512; u += 256) {
    int e = u >> 3, cg = u & 7;
    __align__(16) uint16_t tmp[8];
    for (int j = 0; j < 8; j++) tmp[j] = T[cg * 8 + j][e];
    *(uint4*)&dst[(size_t)e * NS + s0 + cg * 8] = *(uint4*)tmp;
  }
}

#if HAVE_MFMA1K
// ---------------- kernel 2: causal attention, S^T trick + PADDED manual staging ----------------
// S^T = K.Q^T puts P^T directly in B-operand layout of 16x16x16 MFMA; O^T = V^T.P^T in regs.
// K/V^T tiles staged with uint4 into +8-padded LDS (stride 36 dwords: fragment reads ~2-way, free).
__global__ __launch_bounds__(256, 4) void k_attn(
    const uint16_t* __restrict__ Q, const uint16_t* __restrict__ K,
    const uint16_t* __restrict__ VT, uint16_t* __restrict__ Y) {
  __shared__ __align__(16) uint16_t Ks[64][72];   // [key][e]
  __shared__ __align__(16) uint16_t Vs[64][72];   // [e][key]
  int bh = blockIdx.y;
  int b = bh >> 4, h = bh & 15;
  int ta = blockIdx.x;       // 0..15
  int tb = 31 - ta;          // 16..31
  const uint16_t* Qp = Q + (size_t)bh * (NS * NHS);
  const uint16_t* Kp = K + (size_t)bh * (NS * NHS);
  const uint16_t* Vp = VT + (size_t)bh * (NS * NHS);  // [e][key]
  int tid = threadIdx.x;
  int wv = tid >> 6, lane = tid & 63, quad = lane >> 4, l16 = lane & 15;

  // Q fragments from global; B operand of S^T = K.Q^T (n = q-row = l16)
  int rA = ta * 64 + wv * 16 + l16;
  int rB = tb * 64 + wv * 16 + l16;
  bf16x8 aqA0 = *(const bf16x8*)&Qp[(size_t)rA * NHS + quad * 8];
  bf16x8 aqA1 = *(const bf16x8*)&Qp[(size_t)rA * NHS + 32 + quad * 8];
  bf16x8 aqB0 = *(const bf16x8*)&Qp[(size_t)rB * NHS + quad * 8];
  bf16x8 aqB1 = *(const bf16x8*)&Qp[(size_t)rB * NHS + 32 + quad * 8];

  float lAs = 0.f, lBs = 0.f;          // per-lane row-sum (all p of a lane share q-row l16)
  floatx4 oA[4], oB[4];                // O^T accumulators, one per e-tile
  for (int et = 0; et < 4; et++) {
    oA[et] = (floatx4){0.f, 0.f, 0.f, 0.f};
    oB[et] = (floatx4){0.f, 0.f, 0.f, 0.f};
  }

  for (int kt = 0; kt <= tb; kt++) {
    bool doA = (kt <= ta);  // uniform across block
    __syncthreads();
    for (int u = tid; u < 512; u += 256) {
      int row = u >> 3, cg = u & 7;
      *(uint4*)&Ks[row][cg * 8] =
          *(const uint4*)&Kp[(size_t)(kt * 64 + row) * NHS + cg * 8];
    }
    for (int u = tid; u < 512; u += 256) {
      int row = u >> 3, cg = u & 7;   // row = e, cols = keys
      *(uint4*)&Vs[row][cg * 8] =
          *(const uint4*)&Vp[(size_t)row * NS + kt * 64 + cg * 8];
    }
    __syncthreads();

    // ---- S^T tiles + mask + exp2 + pack (P^T lands in B-layout of K=16 MFMA) ----
    s16x4 pbA[4], pbB[4];
    for (int ct = 0; ct < 4; ct++) {
      bf16x8 kb0 = *(const bf16x8*)&Ks[ct * 16 + l16][quad * 8];
      bf16x8 kb1 = *(const bf16x8*)&Ks[ct * 16 + l16][32 + quad * 8];
      int key = kt * 64 + ct * 16 + quad * 4;
      floatx4 c = (floatx4){0.f, 0.f, 0.f, 0.f};
      c = __builtin_amdgcn_mfma_f32_16x16x32_bf16(kb0, aqB0, c, 0, 0, 0);
      c = __builtin_amdgcn_mfma_f32_16x16x32_bf16(kb1, aqB1, c, 0, 0, 0);
      for (int r = 0; r < 4; r++) {
        float s = (kt == tb && key + r > rB) ? NEG_BIG : c[r];
        float p = __builtin_amdgcn_exp2f(s);
        lBs += p;
        pbB[ct][r] = (short)f2b(p);
      }
      if (doA) {
        floatx4 d = (floatx4){0.f, 0.f, 0.f, 0.f};
        d = __builtin_amdgcn_mfma_f32_16x16x32_bf16(kb0, aqA0, d, 0, 0, 0);
        d = __builtin_amdgcn_mfma_f32_16x16x32_bf16(kb1, aqA1, d, 0, 0, 0);
        for (int r = 0; r < 4; r++) {
          float s = (kt == ta && key + r > rA) ? NEG_BIG : d[r];
          float p = __builtin_amdgcn_exp2f(s);
          lAs += p;
          pbA[ct][r] = (short)f2b(p);
        }
      }
    }
    // ---- O^T += V^T . P^T (A-frag = 4 keys of V^T via ds_read_b64, shared A/B) ----
    for (int et = 0; et < 4; et++)
      for (int ct = 0; ct < 4; ct++) {
        s16x4 va = *(const s16x4*)&Vs[et * 16 + l16][ct * 16 + quad * 4];
        oB[et] = __builtin_amdgcn_mfma_f32_16x16x16bf16_1k(va, pbB[ct], oB[et], 0, 0, 0);
        if (doA)
          oA[et] = __builtin_amdgcn_mfma_f32_16x16x16bf16_1k(va, pbA[ct], oA[et], 0, 0, 0);
      }
  }
  // ---- reduce row-sums across the 4 quads, normalize, packed store ----
  lAs += __shfl_xor(lAs, 16, 64); lAs += __shfl_xor(lAs, 32, 64);
  lBs += __shfl_xor(lBs, 16, 64); lBs += __shfl_xor(lBs, 32, 64);
  float invA = 1.f / lAs, invB = 1.f / lBs;
  uint16_t* yb = Y + (size_t)b * NS * ND + (size_t)h * NHS;
  for (int et = 0; et < 4; et++) {
    __align__(8) uint16_t tA[4], tB[4];
    for (int r = 0; r < 4; r++) {
      tA[r] = f2b(oA[et][r] * invA);
      tB[r] = f2b(oB[et][r] * invB);
    }
    *(uint2*)&yb[(size_t)rA * ND + et * 16 + quad * 4] = *(uint2*)tA;
    *(uint2*)&yb[(size_t)rB * ND + et * 16 + quad * 4] = *(uint2*)tB;
  }
}
#else
// ---------------- fallback: round-8 k_attn (LDS-staged K/V + P round-trip) ----------------
__global__ __launch_bounds__(256) void k_attn(
    const uint16_t* __restrict__ Q, const uint16_t* __restrict__ K,
    const uint16_t* __restrict__ VT, uint16_t* __restrict__ Y) {
  __shared__ __align__(16) uint16_t Ks[64][72];
  __shared__ __align__(16) uint16_t Vs[64][72];
  __shared__ __align__(16) uint16_t Ps[4][2][16][72];
  int bh = blockIdx.y;
  int b = bh >> 4, h = bh & 15;
  int ta = blockIdx.x;
  int tb = 31 - ta;
  const uint16_t* Qp = Q + (size_t)bh * (NS * NHS);
  const uint16_t* Kp = K + (size_t)bh * (NS * NHS);
  const uint16_t* Vp = VT + (size_t)bh * (NS * NHS);
  int tid = threadIdx.x;
  int wv = tid >> 6, lane = tid & 63, quad = lane >> 4, l16 = lane & 15;

  int rA = ta * 64 + wv * 16 + l16;
  int rB = tb * 64 + wv * 16 + l16;
  bf16x8 aqA0 = *(const bf16x8*)&Qp[(size_t)rA * NHS + quad * 8];
  bf16x8 aqA1 = *(const bf16x8*)&Qp[(size_t)rA * NHS + 32 + quad * 8];
  bf16x8 aqB0 = *(const bf16x8*)&Qp[(size_t)rB * NHS + quad * 8];
  bf16x8 aqB1 = *(const bf16x8*)&Qp[(size_t)rB * NHS + 32 + quad * 8];

  float lA[4] = {0.f, 0.f, 0.f, 0.f}, lB[4] = {0.f, 0.f, 0.f, 0.f};
  floatx4 oA[4], oB[4];
  for (int ct = 0; ct < 4; ct++) {
    oA[ct] = (floatx4){0.f, 0.f, 0.f, 0.f};
    oB[ct] = (floatx4){0.f, 0.f, 0.f, 0.f};
  }
  for (int kt = 0; kt <= tb; kt++) {
    bool doA = (kt <= ta);
    __syncthreads();
    for (int u = tid; u < 512; u += 256) {
      int row = u >> 3, cg = u & 7;
      *(uint4*)&Ks[row][cg * 8] =
          *(const uint4*)&Kp[(size_t)(kt * 64 + row) * NHS + cg * 8];
    }
    for (int u = tid; u < 512; u += 256) {
      int row = u >> 3, cg = u & 7;
      *(uint4*)&Vs[row][cg * 8] =
          *(const uint4*)&Vp[(size_t)row * NS + kt * 64 + cg * 8];
    }
    __syncthreads();
    floatx4 sA[4], sB[4];
    for (int ct = 0; ct < 4; ct++) {
      bf16x8 kb0 = *(const bf16x8*)&Ks[ct * 16 + l16][quad * 8];
      bf16x8 kb1 = *(const bf16x8*)&Ks[ct * 16 + l16][32 + quad * 8];
      floatx4 c = (floatx4){0.f, 0.f, 0.f, 0.f};
      c = __builtin_amdgcn_mfma_f32_16x16x32_bf16(aqB0, kb0, c, 0, 0, 0);
      c = __builtin_amdgcn_mfma_f32_16x16x32_bf16(aqB1, kb1, c, 0, 0, 0);
      sB[ct] = c;
      if (doA) {
        floatx4 d = (floatx4){0.f, 0.f, 0.f, 0.f};
        d = __builtin_amdgcn_mfma_f32_16x16x32_bf16(aqA0, kb0, d, 0, 0, 0);
        d = __builtin_amdgcn_mfma_f32_16x16x32_bf16(aqA1, kb1, d, 0, 0, 0);
        sA[ct] = d;
      }
    }
    if (kt == tb) {
      int qrb = tb * 64 + wv * 16 + quad * 4;
      for (int ct = 0; ct < 4; ct++) {
        int kg = kt * 64 + ct * 16 + l16;
        for (int r = 0; r < 4; r++)
          sB[ct][r] = (kg <= qrb + r) ? sB[ct][r] : NEG_BIG;
      }
    }
    if (doA && kt == ta) {
      int qrb = ta * 64 + wv * 16 + quad * 4;
      for (int ct = 0; ct < 4; ct++) {
        int kg = kt * 64 + ct * 16 + l16;
        for (int r = 0; r < 4; r++)
          sA[ct][r] = (kg <= qrb + r) ? sA[ct][r] : NEG_BIG;
      }
    }
    for (int ct = 0; ct < 4; ct++)
      for (int r = 0; r < 4; r++) {
        float p = __builtin_amdgcn_exp2f(sB[ct][r]);
        lB[r] += p;
        Ps[wv][1][quad * 4 + r][ct * 16 + l16] = f2b(p);
      }
    if (doA)
      for (int ct = 0; ct < 4; ct++)
        for (int r = 0; r < 4; r++) {
          float p = __builtin_amdgcn_exp2f(sA[ct][r]);
          lA[r] += p;
          Ps[wv][0][quad * 4 + r][ct * 16 + l16] = f2b(p);
        }
    bf16x8 apB0 = *(const bf16x8*)&Ps[wv][1][l16][quad * 8];
    bf16x8 apB1 = *(const bf16x8*)&Ps[wv][1][l16][32 + quad * 8];
    bf16x8 apA0, apA1;
    if (doA) {
      apA0 = *(const bf16x8*)&Ps[wv][0][l16][quad * 8];
      apA1 = *(const bf16x8*)&Ps[wv][0][l16][32 + quad * 8];
    }
    for (int ct = 0; ct < 4; ct++) {
      bf16x8 vb0 = *(const bf16x8*)&Vs[ct * 16 + l16][quad * 8];
      bf16x8 vb1 = *(const bf16x8*)&Vs[ct * 16 + l16][32 + quad * 8];
      oB[ct] = __builtin_amdgcn_mfma_f32_16x16x32_bf16(apB0, vb0, oB[ct], 0, 0, 0);
      oB[ct] = __builtin_amdgcn_mfma_f32_16x16x32_bf16(apB1, vb1, oB[ct], 0, 0, 0);
      if (doA) {
        oA[ct] = __builtin_amdgcn_mfma_f32_16x16x32_bf16(apA0, vb0, oA[ct], 0, 0, 0);
        oA[ct] = __builtin_amdgcn_mfma_f32_16x16x32_bf16(apA1, vb1, oA[ct], 0, 0, 0);
      }
    }
  }
  for (int off = 1; off < 16; off <<= 1)
    for (int r = 0; r < 4; r++) {
      lA[r] += __shfl_xor(lA[r], off, 64);
      lB[r] += __shfl_xor(lB[r], off, 64);
    }
  uint16_t* yb = Y + (size_t)b * NS * ND + (size_t)h * NHS;
  for (int ct = 0; ct < 4; ct++)
    for (int r = 0; r < 4; r++) {
      int sA_ = ta * 64 + wv * 16 + quad * 4 + r;
      int sB_ = tb * 64 + wv * 16 + quad * 4 + r;
      yb[(size_t)sA_ * ND + ct * 16 + l16] = f2b(oA[ct][r] / lA[r]);
      yb[(size_t)sB_ * ND + ct * 16 + l16] = f2b(oB[ct][r] / lB[r]);
    }
}
#endif

// ---------------- kernel 3: output projection + bias, m97-style (fp32 out) ----------------
__global__ __launch_bounds__(256) void k_proj(
    const uint16_t* __restrict__ y, const uint16_t* __restrict__ wot,
    const float* __restrict__ bo, float* __restrict__ out) {
  __shared__ __align__(16) uint16_t As[128 * 64];
  __shared__ __align__(16) uint16_t Bs[128 * 64];
  int m0 = blockIdx.x * 128;
  int n0 = blockIdx.y * 128;
  int tid = threadIdx.x;
  int wv = tid >> 6, lane = tid & 63, quad = lane >> 4, l16 = lane & 15;
  int wr = wv >> 1, wc = wv & 1;
  int srow = lane >> 3, scol = lane & 7;

  floatx4 acc[4][4];
  for (int i = 0; i < 4; i++)
    for (int j = 0; j < 4; j++) acc[i][j] = (floatx4){0.f, 0.f, 0.f, 0.f};

  for (int k0 = 0; k0 < ND; k0 += 64) {
    __syncthreads();
    for (int j = 0; j < 4; j++) {
      int rg = wv * 4 + j;
      int r = rg * 8 + srow;
      gll16(&y[(size_t)(m0 + r) * ND + k0 + scol * 8], &As[rg * 512]);
      gll16(&wot[(size_t)(n0 + r) * ND + k0 + scol * 8], &Bs[rg * 512]);
    }
    __syncthreads();
    for (int kk = 0; kk < 2; kk++) {
      bf16x8 af[4], bfr[4];
      for (int t = 0; t < 4; t++) {
        af[t]  = *(const bf16x8*)&As[(wr * 64 + t * 16 + l16) * 64 + kk * 32 + quad * 8];
        bfr[t] = *(const bf16x8*)&Bs[(wc * 64 + t * 16 + l16) * 64 + kk * 32 + quad * 8];
      }
      for (int mt = 0; mt < 4; mt++)
        for (int nt = 0; nt < 4; nt++)
          acc[mt][nt] = __builtin_amdgcn_mfma_f32_16x16x32_bf16(af[mt], bfr[nt], acc[mt][nt], 0, 0, 0);
    }
  }
  for (int mt = 0; mt < 4; mt++)
    for (int nt = 0; nt < 4; nt++)
      for (int r = 0; r < 4; r++) {
        int s = m0 + wr * 64 + mt * 16 + quad * 4 + r;
        int n = n0 + wc * 64 + nt * 16 + l16;
        out[(size_t)s * ND + n] = acc[mt][nt][r] + bo[n];
      }
}

extern "C" void kernel_launch(void* const* d_in, const int* in_sizes, int n_in,
                              void* d_out, int out_size, void* d_ws, size_t ws_size,
                              hipStream_t stream) {
  const float* x  = (const float*)d_in[0];
  const float* Wq = (const float*)d_in[1];
  const float* Wk = (const float*)d_in[2];
  const float* Wv = (const float*)d_in[3];
  const float* Wo = (const float*)d_in[4];
  const float* bo = (const float*)d_in[5];
  uint16_t* ws = (uint16_t*)d_ws;

  uint16_t* wt = ws;                       // 4 * WSLAB bf16 (Wq_t, Wk_t, Wv_t, Wo_t)
  uint16_t* xb = ws + 4 * WSLAB;           // XSLAB bf16
  uint16_t* q  = xb + XSLAB;               // QSLAB each
  uint16_t* k  = q + QSLAB;
  uint16_t* v  = k + QSLAB;
  uint16_t* y  = v + QSLAB;
  uint16_t* vt = y + QSLAB;                // QSLAB (V transposed)

  k_prep<<<dim3(5120), dim3(256), 0, stream>>>(x, Wq, Wk, Wv, Wo, xb, wt);
  k_qkv<<<dim3(64, 24), dim3(256), 0, stream>>>(xb, wt, q);
  k_vt<<<dim3(NS / 64, NB * NH), dim3(256), 0, stream>>>(v, vt);
  k_attn<<<dim3(16, NB * NH), dim3(256), 0, stream>>>(q, k, vt, y);
  k_proj<<<dim3(64, 8), dim3(256), 0, stream>>>(y, wt + 3 * WSLAB, bo, (float*)d_out);
}

// Round 11
// 274.725 us; speedup vs baseline: 1.8313x; 1.1159x over previous
//
#include <hip/hip_runtime.h>
#include <hip/hip_bf16.h>
#include <stdint.h>

#define NB 4
#define NS 2048
#define ND 1024
#define NH 16
#define NHS 64
#define NEG_BIG (-1e30f)
// 1/sqrt(HS) * log2(e): folds softmax exp->exp2 into Q scaling (exactly softmax-invariant)
#define Q_SCALE 0.18033688011112042f

typedef __bf16 bf16x8 __attribute__((ext_vector_type(8)));
typedef float floatx4 __attribute__((ext_vector_type(4)));
typedef short s16x4 __attribute__((ext_vector_type(4)));

#if defined(__has_builtin)
#if __has_builtin(__builtin_amdgcn_mfma_f32_16x16x16bf16_1k)
#define HAVE_MFMA1K 1
#endif
#endif
#ifndef HAVE_MFMA1K
#define HAVE_MFMA1K 0
#endif

static constexpr size_t WSLAB = (size_t)NH * ND * NHS;        // 2^20 elems per weight mat
static constexpr size_t QSLAB = (size_t)NB * NH * NS * NHS;   // 8M elems per QKV/Y slab
static constexpr size_t XSLAB = (size_t)NB * NS * ND;         // 8M elems (x as bf16)

__device__ __forceinline__ uint16_t f2b(float f) {
    union { __hip_bfloat16 h; uint16_t u; } cv;
    cv.h = __float2bfloat16(f);
    return cv.u;
}

// async global->LDS, 16B per lane. LDS dest = wave-uniform base + lane*16 (UNPADDED only).
__device__ __forceinline__ void gll16(const void* g, void* l) {
  __builtin_amdgcn_global_load_lds(
      (__attribute__((address_space(1))) void*)(uintptr_t)g,
      (__attribute__((address_space(3))) void*)(uintptr_t)l,
      16, 0, 0);
}

// ---------------- kernel P: merged x-convert + weight convert/transpose ----------------
__global__ __launch_bounds__(256) void k_prep(
    const float* __restrict__ x, const float* __restrict__ Wq,
    const float* __restrict__ Wk, const float* __restrict__ Wv,
    const float* __restrict__ Wo, uint16_t* __restrict__ xb,
    uint16_t* __restrict__ wt) {
  __shared__ __align__(16) uint16_t T[64][72];
  int bid = blockIdx.x;
  int tid = threadIdx.x;
  if (bid < 4096) {
    size_t i0 = ((size_t)bid * 256 + tid) * 8;
    float4 f0 = *(const float4*)&x[i0];
    float4 f1 = *(const float4*)&x[i0 + 4];
    __align__(16) uint16_t tmp[8];
    tmp[0] = f2b(f0.x); tmp[1] = f2b(f0.y); tmp[2] = f2b(f0.z); tmp[3] = f2b(f0.w);
    tmp[4] = f2b(f1.x); tmp[5] = f2b(f1.y); tmp[6] = f2b(f1.z); tmp[7] = f2b(f1.w);
    *(uint4*)&xb[i0] = *(uint4*)tmp;
    return;
  }
  bid -= 4096;
  const float* src; uint16_t* dst;
  int srcStride, dstStride, r0, c0;
  if (bid < 768) {
    int mat = bid >> 8;
    int rem = bid & 255;
    int h = rem >> 4, dt = rem & 15;
    const float* W = (mat == 0) ? Wq : (mat == 1) ? Wk : Wv;
    src = W + (size_t)h * (ND * NHS);
    dst = wt + (size_t)mat * WSLAB + (size_t)h * (NHS * ND);
    srcStride = NHS; dstStride = ND;
    r0 = dt * 64; c0 = 0;
  } else {
    int rem = bid - 768;
    int dt = rem >> 4, et = rem & 15;
    src = Wo; dst = wt + 3 * WSLAB;
    srcStride = ND; dstStride = ND;
    r0 = dt * 64; c0 = et * 64;
  }
  for (int u = tid; u < 1024; u += 256) {
    int row = u >> 4, cq = u & 15;
    float4 f = *(const float4*)&src[(size_t)(r0 + row) * srcStride + c0 + cq * 4];
    uint16_t* p = &T[row][cq * 4];
    p[0] = f2b(f.x); p[1] = f2b(f.y); p[2] = f2b(f.z); p[3] = f2b(f.w);
  }
  __syncthreads();
  for (int u = tid; u < 512; u += 256) {
    int c = u >> 3, cg = u & 7;
    __align__(16) uint16_t tmp[8];
    for (int j = 0; j < 8; j++) tmp[j] = T[cg * 8 + j][c];
    *(uint4*)&dst[(size_t)(c0 + c) * dstStride + r0 + cg * 8] = *(uint4*)tmp;
  }
}

// ---------------- kernel 1: fused QKV GEMM, m97-style ----------------
__global__ __launch_bounds__(256) void k_qkv(
    const uint16_t* __restrict__ xb, const uint16_t* __restrict__ wt,
    uint16_t* __restrict__ qkv) {
  __shared__ __align__(16) uint16_t As[128 * 64];
  __shared__ __align__(16) uint16_t Bs[128 * 64];
  int m0 = blockIdx.x * 128;
  int n0 = blockIdx.y * 128;
  int tid = threadIdx.x;
  int wv = tid >> 6, lane = tid & 63, quad = lane >> 4, l16 = lane & 15;
  int wr = wv >> 1, wc = wv & 1;
  int srow = lane >> 3, scol = lane & 7;

  floatx4 acc[4][4];
  for (int i = 0; i < 4; i++)
    for (int j = 0; j < 4; j++) acc[i][j] = (floatx4){0.f, 0.f, 0.f, 0.f};

  for (int k0 = 0; k0 < ND; k0 += 64) {
    __syncthreads();
    for (int j = 0; j < 4; j++) {
      int rg = wv * 4 + j;
      int r = rg * 8 + srow;
      gll16(&xb[(size_t)(m0 + r) * ND + k0 + scol * 8], &As[rg * 512]);
      gll16(&wt[(size_t)(n0 + r) * ND + k0 + scol * 8], &Bs[rg * 512]);
    }
    __syncthreads();
    for (int kk = 0; kk < 2; kk++) {
      bf16x8 af[4], bfr[4];
      for (int t = 0; t < 4; t++) {
        af[t]  = *(const bf16x8*)&As[(wr * 64 + t * 16 + l16) * 64 + kk * 32 + quad * 8];
        bfr[t] = *(const bf16x8*)&Bs[(wc * 64 + t * 16 + l16) * 64 + kk * 32 + quad * 8];
      }
      for (int mt = 0; mt < 4; mt++)
        for (int nt = 0; nt < 4; nt++)
          acc[mt][nt] = __builtin_amdgcn_mfma_f32_16x16x32_bf16(af[mt], bfr[nt], acc[mt][nt], 0, 0, 0);
    }
  }
  int mat = n0 >> 10;
  float scale = (mat == 0) ? Q_SCALE : 1.0f;
  uint16_t* base = qkv + (size_t)mat * QSLAB;
  for (int mt = 0; mt < 4; mt++)
    for (int nt = 0; nt < 4; nt++)
      for (int r = 0; r < 4; r++) {
        int m = m0 + wr * 64 + mt * 16 + quad * 4 + r;
        int n = (n0 & 1023) + wc * 64 + nt * 16 + l16;
        int b = m >> 11, s = m & 2047;
        int h = n >> 6, e = n & 63;
        base[((size_t)(b * 16 + h) * NS + s) * NHS + e] = f2b(acc[mt][nt][r] * scale);
      }
}

// ---------------- kernel 1b: V -> V^T ([B,H,S,HS] -> [B,H,HS,S]) ----------------
__global__ __launch_bounds__(256) void k_vt(
    const uint16_t* __restrict__ v, uint16_t* __restrict__ vt) {
  __shared__ __align__(16) uint16_t T[64][72];
  int bh = blockIdx.y;
  int s0 = blockIdx.x * 64;
  int tid = threadIdx.x;
  const uint16_t* src = v + (size_t)bh * (NS * NHS);
  uint16_t* dst = vt + (size_t)bh * (NS * NHS);
  for (int u = tid; u < 512; u += 256) {
    int row = u >> 3, cg = u & 7;
    *(uint4*)&T[row][cg * 8] =
        *(const uint4*)&src[(size_t)(s0 + row) * NHS + cg * 8];
  }
  __syncthreads();
  for (int u = tid; u < 512; u += 256) {
    int e = u >> 3, cg = u & 7;
    __align__(16) uint16_t tmp[8];
    for (int j = 0; j < 8; j++) tmp[j] = T[cg * 8 + j][e];
    *(uint4*)&dst[(size_t)e * NS + s0 + cg * 8] = *(uint4*)tmp;
  }
}

#if HAVE_MFMA1K
// ---------------- kernel 2: causal attention, S^T trick + reg-prefetch double-buffer ----------------
// S^T = K.Q^T puts P^T directly in B-operand layout of 16x16x16 MFMA; O^T = V^T.P^T in regs.
// K/V^T tile kt+1 prefetched into VGPRs while computing tile kt; regs flushed to padded
// LDS between barriers. Global-load latency overlaps the whole compute phase.
__global__ __launch_bounds__(256, 4) void k_attn(
    const uint16_t* __restrict__ Q, const uint16_t* __restrict__ K,
    const uint16_t* __restrict__ VT, uint16_t* __restrict__ Y) {
  __shared__ __align__(16) uint16_t Ks[64][72];   // [key][e]
  __shared__ __align__(16) uint16_t Vs[64][72];   // [e][key]
  int bh = blockIdx.y;
  int b = bh >> 4, h = bh & 15;
  int ta = blockIdx.x;       // 0..15
  int tb = 31 - ta;          // 16..31
  const uint16_t* Qp = Q + (size_t)bh * (NS * NHS);
  const uint16_t* Kp = K + (size_t)bh * (NS * NHS);
  const uint16_t* Vp = VT + (size_t)bh * (NS * NHS);  // [e][key]
  int tid = threadIdx.x;
  int wv = tid >> 6, lane = tid & 63, quad = lane >> 4, l16 = lane & 15;

  // staging map: each thread covers u = tid and tid+256 (row = u>>3, 16B col = u&7)
  int row0 = tid >> 3, cg0 = tid & 7;
  int row1 = (tid + 256) >> 3, cg1 = tid & 7;

  // Q fragments from global; B operand of S^T = K.Q^T (n = q-row = l16)
  int rA = ta * 64 + wv * 16 + l16;
  int rB = tb * 64 + wv * 16 + l16;
  bf16x8 aqA0 = *(const bf16x8*)&Qp[(size_t)rA * NHS + quad * 8];
  bf16x8 aqA1 = *(const bf16x8*)&Qp[(size_t)rA * NHS + 32 + quad * 8];
  bf16x8 aqB0 = *(const bf16x8*)&Qp[(size_t)rB * NHS + quad * 8];
  bf16x8 aqB1 = *(const bf16x8*)&Qp[(size_t)rB * NHS + 32 + quad * 8];

  float lAs = 0.f, lBs = 0.f;          // per-lane row-sum (all p of a lane share q-row l16)
  floatx4 oA[4], oB[4];                // O^T accumulators, one per e-tile
  for (int et = 0; et < 4; et++) {
    oA[et] = (floatx4){0.f, 0.f, 0.f, 0.f};
    oB[et] = (floatx4){0.f, 0.f, 0.f, 0.f};
  }

  // prefetch tile 0 into registers
  uint4 rk0, rk1, rv0, rv1;
  rk0 = *(const uint4*)&Kp[(size_t)(0 * 64 + row0) * NHS + cg0 * 8];
  rk1 = *(const uint4*)&Kp[(size_t)(0 * 64 + row1) * NHS + cg1 * 8];
  rv0 = *(const uint4*)&Vp[(size_t)row0 * NS + 0 * 64 + cg0 * 8];
  rv1 = *(const uint4*)&Vp[(size_t)row1 * NS + 0 * 64 + cg1 * 8];

  for (int kt = 0; kt <= tb; kt++) {
    bool doA = (kt <= ta);  // uniform across block
    __syncthreads();        // readers of previous tile done
    *(uint4*)&Ks[row0][cg0 * 8] = rk0;
    *(uint4*)&Ks[row1][cg1 * 8] = rk1;
    *(uint4*)&Vs[row0][cg0 * 8] = rv0;
    *(uint4*)&Vs[row1][cg1 * 8] = rv1;
    __syncthreads();        // tile kt visible
    if (kt < tb) {          // issue prefetch of kt+1; consumed after next barrier
      rk0 = *(const uint4*)&Kp[(size_t)((kt + 1) * 64 + row0) * NHS + cg0 * 8];
      rk1 = *(const uint4*)&Kp[(size_t)((kt + 1) * 64 + row1) * NHS + cg1 * 8];
      rv0 = *(const uint4*)&Vp[(size_t)row0 * NS + (kt + 1) * 64 + cg0 * 8];
      rv1 = *(const uint4*)&Vp[(size_t)row1 * NS + (kt + 1) * 64 + cg1 * 8];
    }

    // ---- S^T tiles + mask + exp2 + pack (P^T lands in B-layout of K=16 MFMA) ----
    s16x4 pbA[4], pbB[4];
    for (int ct = 0; ct < 4; ct++) {
      bf16x8 kb0 = *(const bf16x8*)&Ks[ct * 16 + l16][quad * 8];
      bf16x8 kb1 = *(const bf16x8*)&Ks[ct * 16 + l16][32 + quad * 8];
      int key = kt * 64 + ct * 16 + quad * 4;
      floatx4 c = (floatx4){0.f, 0.f, 0.f, 0.f};
      c = __builtin_amdgcn_mfma_f32_16x16x32_bf16(kb0, aqB0, c, 0, 0, 0);
      c = __builtin_amdgcn_mfma_f32_16x16x32_bf16(kb1, aqB1, c, 0, 0, 0);
      for (int r = 0; r < 4; r++) {
        float s = (kt == tb && key + r > rB) ? NEG_BIG : c[r];
        float p = __builtin_amdgcn_exp2f(s);
        lBs += p;
        pbB[ct][r] = (short)f2b(p);
      }
      if (doA) {
        floatx4 d = (floatx4){0.f, 0.f, 0.f, 0.f};
        d = __builtin_amdgcn_mfma_f32_16x16x32_bf16(kb0, aqA0, d, 0, 0, 0);
        d = __builtin_amdgcn_mfma_f32_16x16x32_bf16(kb1, aqA1, d, 0, 0, 0);
        for (int r = 0; r < 4; r++) {
          float s = (kt == ta && key + r > rA) ? NEG_BIG : d[r];
          float p = __builtin_amdgcn_exp2f(s);
          lAs += p;
          pbA[ct][r] = (short)f2b(p);
        }
      }
    }
    // ---- O^T += V^T . P^T (A-frag = 4 keys of V^T via ds_read_b64, shared A/B) ----
    for (int et = 0; et < 4; et++)
      for (int ct = 0; ct < 4; ct++) {
        s16x4 va = *(const s16x4*)&Vs[et * 16 + l16][ct * 16 + quad * 4];
        oB[et] = __builtin_amdgcn_mfma_f32_16x16x16bf16_1k(va, pbB[ct], oB[et], 0, 0, 0);
        if (doA)
          oA[et] = __builtin_amdgcn_mfma_f32_16x16x16bf16_1k(va, pbA[ct], oA[et], 0, 0, 0);
      }
  }
  // ---- reduce row-sums across the 4 quads, normalize, packed store ----
  lAs += __shfl_xor(lAs, 16, 64); lAs += __shfl_xor(lAs, 32, 64);
  lBs += __shfl_xor(lBs, 16, 64); lBs += __shfl_xor(lBs, 32, 64);
  float invA = 1.f / lAs, invB = 1.f / lBs;
  uint16_t* yb = Y + (size_t)b * NS * ND + (size_t)h * NHS;
  for (int et = 0; et < 4; et++) {
    __align__(8) uint16_t tA[4], tB[4];
    for (int r = 0; r < 4; r++) {
      tA[r] = f2b(oA[et][r] * invA);
      tB[r] = f2b(oB[et][r] * invB);
    }
    *(uint2*)&yb[(size_t)rA * ND + et * 16 + quad * 4] = *(uint2*)tA;
    *(uint2*)&yb[(size_t)rB * ND + et * 16 + quad * 4] = *(uint2*)tB;
  }
}
#else
// ---------------- fallback: round-8 k_attn (LDS-staged K/V + P round-trip) ----------------
__global__ __launch_bounds__(256) void k_attn(
    const uint16_t* __restrict__ Q, const uint16_t* __restrict__ K,
    const uint16_t* __restrict__ VT, uint16_t* __restrict__ Y) {
  __shared__ __align__(16) uint16_t Ks[64][72];
  __shared__ __align__(16) uint16_t Vs[64][72];
  __shared__ __align__(16) uint16_t Ps[4][2][16][72];
  int bh = blockIdx.y;
  int b = bh >> 4, h = bh & 15;
  int ta = blockIdx.x;
  int tb = 31 - ta;
  const uint16_t* Qp = Q + (size_t)bh * (NS * NHS);
  const uint16_t* Kp = K + (size_t)bh * (NS * NHS);
  const uint16_t* Vp = VT + (size_t)bh * (NS * NHS);
  int tid = threadIdx.x;
  int wv = tid >> 6, lane = tid & 63, quad = lane >> 4, l16 = lane & 15;

  int rA = ta * 64 + wv * 16 + l16;
  int rB = tb * 64 + wv * 16 + l16;
  bf16x8 aqA0 = *(const bf16x8*)&Qp[(size_t)rA * NHS + quad * 8];
  bf16x8 aqA1 = *(const bf16x8*)&Qp[(size_t)rA * NHS + 32 + quad * 8];
  bf16x8 aqB0 = *(const bf16x8*)&Qp[(size_t)rB * NHS + quad * 8];
  bf16x8 aqB1 = *(const bf16x8*)&Qp[(size_t)rB * NHS + 32 + quad * 8];

  float lA[4] = {0.f, 0.f, 0.f, 0.f}, lB[4] = {0.f, 0.f, 0.f, 0.f};
  floatx4 oA[4], oB[4];
  for (int ct = 0; ct < 4; ct++) {
    oA[ct] = (floatx4){0.f, 0.f, 0.f, 0.f};
    oB[ct] = (floatx4){0.f, 0.f, 0.f, 0.f};
  }
  for (int kt = 0; kt <= tb; kt++) {
    bool doA = (kt <= ta);
    __syncthreads();
    for (int u = tid; u < 512; u += 256) {
      int row = u >> 3, cg = u & 7;
      *(uint4*)&Ks[row][cg * 8] =
          *(const uint4*)&Kp[(size_t)(kt * 64 + row) * NHS + cg * 8];
    }
    for (int u = tid; u < 512; u += 256) {
      int row = u >> 3, cg = u & 7;
      *(uint4*)&Vs[row][cg * 8] =
          *(const uint4*)&Vp[(size_t)row * NS + kt * 64 + cg * 8];
    }
    __syncthreads();
    floatx4 sA[4], sB[4];
    for (int ct = 0; ct < 4; ct++) {
      bf16x8 kb0 = *(const bf16x8*)&Ks[ct * 16 + l16][quad * 8];
      bf16x8 kb1 = *(const bf16x8*)&Ks[ct * 16 + l16][32 + quad * 8];
      floatx4 c = (floatx4){0.f, 0.f, 0.f, 0.f};
      c = __builtin_amdgcn_mfma_f32_16x16x32_bf16(aqB0, kb0, c, 0, 0, 0);
      c = __builtin_amdgcn_mfma_f32_16x16x32_bf16(aqB1, kb1, c, 0, 0, 0);
      sB[ct] = c;
      if (doA) {
        floatx4 d = (floatx4){0.f, 0.f, 0.f, 0.f};
        d = __builtin_amdgcn_mfma_f32_16x16x32_bf16(aqA0, kb0, d, 0, 0, 0);
        d = __builtin_amdgcn_mfma_f32_16x16x32_bf16(aqA1, kb1, d, 0, 0, 0);
        sA[ct] = d;
      }
    }
    if (kt == tb) {
      int qrb = tb * 64 + wv * 16 + quad * 4;
      for (int ct = 0; ct < 4; ct++) {
        int kg = kt * 64 + ct * 16 + l16;
        for (int r = 0; r < 4; r++)
          sB[ct][r] = (kg <= qrb + r) ? sB[ct][r] : NEG_BIG;
      }
    }
    if (doA && kt == ta) {
      int qrb = ta * 64 + wv * 16 + quad * 4;
      for (int ct = 0; ct < 4; ct++) {
        int kg = kt * 64 + ct * 16 + l16;
        for (int r = 0; r < 4; r++)
          sA[ct][r] = (kg <= qrb + r) ? sA[ct][r] : NEG_BIG;
      }
    }
    for (int ct = 0; ct < 4; ct++)
      for (int r = 0; r < 4; r++) {
        float p = __builtin_amdgcn_exp2f(sB[ct][r]);
        lB[r] += p;
        Ps[wv][1][quad * 4 + r][ct * 16 + l16] = f2b(p);
      }
    if (doA)
      for (int ct = 0; ct < 4; ct++)
        for (int r = 0; r < 4; r++) {
          float p = __builtin_amdgcn_exp2f(sA[ct][r]);
          lA[r] += p;
          Ps[wv][0][quad * 4 + r][ct * 16 + l16] = f2b(p);
        }
    bf16x8 apB0 = *(const bf16x8*)&Ps[wv][1][l16][quad * 8];
    bf16x8 apB1 = *(const bf16x8*)&Ps[wv][1][l16][32 + quad * 8];
    bf16x8 apA0, apA1;
    if (doA) {
      apA0 = *(const bf16x8*)&Ps[wv][0][l16][quad * 8];
      apA1 = *(const bf16x8*)&Ps[wv][0][l16][32 + quad * 8];
    }
    for (int ct = 0; ct < 4; ct++) {
      bf16x8 vb0 = *(const bf16x8*)&Vs[ct * 16 + l16][quad * 8];
      bf16x8 vb1 = *(const bf16x8*)&Vs[ct * 16 + l16][32 + quad * 8];
      oB[ct] = __builtin_amdgcn_mfma_f32_16x16x32_bf16(apB0, vb0, oB[ct], 0, 0, 0);
      oB[ct] = __builtin_amdgcn_mfma_f32_16x16x32_bf16(apB1, vb1, oB[ct], 0, 0, 0);
      if (doA) {
        oA[ct] = __builtin_amdgcn_mfma_f32_16x16x32_bf16(apA0, vb0, oA[ct], 0, 0, 0);
        oA[ct] = __builtin_amdgcn_mfma_f32_16x16x32_bf16(apA1, vb1, oA[ct], 0, 0, 0);
      }
    }
  }
  for (int off = 1; off < 16; off <<= 1)
    for (int r = 0; r < 4; r++) {
      lA[r] += __shfl_xor(lA[r], off, 64);
      lB[r] += __shfl_xor(lB[r], off, 64);
    }
  uint16_t* yb = Y + (size_t)b * NS * ND + (size_t)h * NHS;
  for (int ct = 0; ct < 4; ct++)
    for (int r = 0; r < 4; r++) {
      int sA_ = ta * 64 + wv * 16 + quad * 4 + r;
      int sB_ = tb * 64 + wv * 16 + quad * 4 + r;
      yb[(size_t)sA_ * ND + ct * 16 + l16] = f2b(oA[ct][r] / lA[r]);
      yb[(size_t)sB_ * ND + ct * 16 + l16] = f2b(oB[ct][r] / lB[r]);
    }
}
#endif

// ---------------- kernel 3: output projection + bias, m97-style (fp32 out) ----------------
__global__ __launch_bounds__(256) void k_proj(
    const uint16_t* __restrict__ y, const uint16_t* __restrict__ wot,
    const float* __restrict__ bo, float* __restrict__ out) {
  __shared__ __align__(16) uint16_t As[128 * 64];
  __shared__ __align__(16) uint16_t Bs[128 * 64];
  int m0 = blockIdx.x * 128;
  int n0 = blockIdx.y * 128;
  int tid = threadIdx.x;
  int wv = tid >> 6, lane = tid & 63, quad = lane >> 4, l16 = lane & 15;
  int wr = wv >> 1, wc = wv & 1;
  int srow = lane >> 3, scol = lane & 7;

  floatx4 acc[4][4];
  for (int i = 0; i < 4; i++)
    for (int j = 0; j < 4; j++) acc[i][j] = (floatx4){0.f, 0.f, 0.f, 0.f};

  for (int k0 = 0; k0 < ND; k0 += 64) {
    __syncthreads();
    for (int j = 0; j < 4; j++) {
      int rg = wv * 4 + j;
      int r = rg * 8 + srow;
      gll16(&y[(size_t)(m0 + r) * ND + k0 + scol * 8], &As[rg * 512]);
      gll16(&wot[(size_t)(n0 + r) * ND + k0 + scol * 8], &Bs[rg * 512]);
    }
    __syncthreads();
    for (int kk = 0; kk < 2; kk++) {
      bf16x8 af[4], bfr[4];
      for (int t = 0; t < 4; t++) {
        af[t]  = *(const bf16x8*)&As[(wr * 64 + t * 16 + l16) * 64 + kk * 32 + quad * 8];
        bfr[t] = *(const bf16x8*)&Bs[(wc * 64 + t * 16 + l16) * 64 + kk * 32 + quad * 8];
      }
      for (int mt = 0; mt < 4; mt++)
        for (int nt = 0; nt < 4; nt++)
          acc[mt][nt] = __builtin_amdgcn_mfma_f32_16x16x32_bf16(af[mt], bfr[nt], acc[mt][nt], 0, 0, 0);
    }
  }
  for (int mt = 0; mt < 4; mt++)
    for (int nt = 0; nt < 4; nt++)
      for (int r = 0; r < 4; r++) {
        int s = m0 + wr * 64 + mt * 16 + quad * 4 + r;
        int n = n0 + wc * 64 + nt * 16 + l16;
        out[(size_t)s * ND + n] = acc[mt][nt][r] + bo[n];
      }
}

extern "C" void kernel_launch(void* const* d_in, const int* in_sizes, int n_in,
                              void* d_out, int out_size, void* d_ws, size_t ws_size,
                              hipStream_t stream) {
  const float* x  = (const float*)d_in[0];
  const float* Wq = (const float*)d_in[1];
  const float* Wk = (const float*)d_in[2];
  const float* Wv = (const float*)d_in[3];
  const float* Wo = (const float*)d_in[4];
  const float* bo = (const float*)d_in[5];
  uint16_t* ws = (uint16_t*)d_ws;

  uint16_t* wt = ws;                       // 4 * WSLAB bf16 (Wq_t, Wk_t, Wv_t, Wo_t)
  uint16_t* xb = ws + 4 * WSLAB;           // XSLAB bf16
  uint16_t* q  = xb + XSLAB;               // QSLAB each
  uint16_t* k  = q + QSLAB;
  uint16_t* v  = k + QSLAB;
  uint16_t* y  = v + QSLAB;
  uint16_t* vt = y + QSLAB;                // QSLAB (V transposed)

  k_prep<<<dim3(5120), dim3(256), 0, stream>>>(x, Wq, Wk, Wv, Wo, xb, wt);
  k_qkv<<<dim3(64, 24), dim3(256), 0, stream>>>(xb, wt, q);
  k_vt<<<dim3(NS / 64, NB * NH), dim3(256), 0, stream>>>(v, vt);
  k_attn<<<dim3(16, NB * NH), dim3(256), 0, stream>>>(q, k, vt, y);
  k_proj<<<dim3(64, 8), dim3(256), 0, stream>>>(y, wt + 3 * WSLAB, bo, (float*)d_out);
}